// Round 13
// baseline (869.339 us; speedup 1.0000x reference)
//
#include <hip/hip_runtime.h>

#define T_SEQ   2048
#define D_MODEL 1024
#define NHEAD   16
#define NEXP    8
#define HID_DIM 2048
#define NTOK    4096
#define MAXBLK  72
#define SLOTS   9216

typedef unsigned short u16;
typedef unsigned int   u32;
typedef __bf16 bf16_t;
typedef bf16_t bf16x8 __attribute__((ext_vector_type(8)));
typedef float  f32x4  __attribute__((ext_vector_type(4)));
typedef float  f32x2  __attribute__((ext_vector_type(2)));
typedef u32    u32x4  __attribute__((ext_vector_type(4)));

typedef __attribute__((address_space(1))) const void* gptr1_t;
typedef __attribute__((address_space(3))) void*       lptr3_t;

__device__ __forceinline__ u16 f2bf_bits(float f) {
  u32 u = __builtin_bit_cast(u32, f);
  u += 0x7FFFu + ((u >> 16) & 1u);
  return (u16)(u >> 16);
}
__device__ __forceinline__ float bf2f(u16 s) {
  return __builtin_bit_cast(float, (u32)s << 16);
}
__device__ __forceinline__ bf16x8 frag_b128(const u16* p) {
  return *reinterpret_cast<const bf16x8*>(p);
}
__device__ __forceinline__ u16 cvt_bf16(float f) {
  return __builtin_bit_cast(u16, (__bf16)f);
}
#define MFMA16(a,b,c) __builtin_amdgcn_mfma_f32_16x16x32_bf16((a),(b),(c),0,0,0)

// ---- async global->LDS, 16B per lane, wave-uniform LDS base ----
__device__ __forceinline__ void gload16(const void* g, void* l) {
  __builtin_amdgcn_global_load_lds((gptr1_t)g, (lptr3_t)l, 16, 0, 0);
}

// ---- BK=32 tile staging: [128][32]-u16, source-side XOR swizzle ----
__device__ __forceinline__ void stage128x32(const u16* gbase, size_t ldk, int kt,
                                            u16* lds, int wid, int lane) {
  int rl = lane >> 2, cc = lane & 3;
#pragma unroll
  for (int h = 0; h < 2; ++h) {
    int row = wid*32 + h*16 + rl;
    int chunk = cc ^ ((row >> 1) & 3);
    gload16(gbase + (size_t)row*ldk + kt + chunk*8, lds + (size_t)(wid*32 + h*16)*32);
  }
}
__device__ __forceinline__ bf16x8 fragLDS(const u16* lds, int row, int l4, int l15) {
  int chunk = l4 ^ ((l15 >> 1) & 3);
  return frag_b128(lds + row*32 + chunk*8);
}

// ---- BK=64 tile staging: [128][64]-u16, chunk = cc ^ (row&7) ----
__device__ __forceinline__ void stage128x64(const u16* gbase, size_t ldk, int kt,
                                            u16* lds, int wid, int lane) {
  int rl = lane >> 3, cc = lane & 7;
#pragma unroll
  for (int g = 0; g < 4; ++g) {
    int row = wid*32 + g*8 + rl;
    int chunk = cc ^ (row & 7);
    gload16(gbase + (size_t)row*ldk + kt + chunk*8, lds + (size_t)(wid*32 + g*8)*64);
  }
}
// ---- BK=64, 64-row tile staging: [64][64]-u16 ----
__device__ __forceinline__ void stage64x64(const u16* gbase, size_t ldk, int kt,
                                           u16* lds, int wid, int lane) {
  int rl = lane >> 3, cc = lane & 7;
#pragma unroll
  for (int g = 0; g < 2; ++g) {
    int row = wid*16 + g*8 + rl;
    int chunk = cc ^ (row & 7);
    gload16(gbase + (size_t)row*ldk + kt + chunk*8, lds + (size_t)(wid*16 + g*8)*64);
  }
}
__device__ __forceinline__ bf16x8 fragLDS64(const u16* lds, int row, int s, int l4, int l15) {
  int chunk = (s*4 + l4) ^ (l15 & 7);   // row&7 == l15&7 (row = 16m + l15)
  return frag_b128(lds + row*64 + chunk*8);
}

// ================= rmsnorm (optionally split hi/lo bf16) =================
template<int SPLIT>
__global__ __launch_bounds__(256) void rmsnorm_kernel(
    const float* __restrict__ x, const float* __restrict__ w,
    u16* __restrict__ hi, u16* __restrict__ lo)
{
  int row = blockIdx.x, tid = threadIdx.x;
  const float* xr = x + (size_t)row * D_MODEL;
  f32x4 v = *reinterpret_cast<const f32x4*>(xr + tid * 4);
  float ss = v[0]*v[0] + v[1]*v[1] + v[2]*v[2] + v[3]*v[3];
#pragma unroll
  for (int off = 32; off >= 1; off >>= 1) ss += __shfl_xor(ss, off);
  __shared__ float part[4];
  if ((tid & 63) == 0) part[tid >> 6] = ss;
  __syncthreads();
  float rms = rsqrtf((part[0]+part[1]+part[2]+part[3]) * (1.0f/D_MODEL) + 1e-6f);
  f32x4 wv = *reinterpret_cast<const f32x4*>(w + tid * 4);
  u32 hw0=0, hw1=0, lw0=0, lw1=0;
#pragma unroll
  for (int j = 0; j < 4; ++j) {
    float f = v[j] * rms * wv[j];
    u16 hb = f2bf_bits(f);
    if (j < 2) hw0 |= (u32)hb << (16*j); else hw1 |= (u32)hb << (16*(j-2));
    if (SPLIT) {
      u16 lb = f2bf_bits(f - bf2f(hb));
      if (j < 2) lw0 |= (u32)lb << (16*j); else lw1 |= (u32)lb << (16*(j-2));
    }
  }
  u32* hp = reinterpret_cast<u32*>(hi + (size_t)row * D_MODEL + tid * 4);
  hp[0] = hw0; hp[1] = hw1;
  if (SPLIT) {
    u32* lp = reinterpret_cast<u32*>(lo + (size_t)row * D_MODEL + tid * 4);
    lp[0] = lw0; lp[1] = lw1;
  }
}

// ================= weight prep: transpose f32 [R][C] -> bf16 [C][R] =================
template<int SPLIT>
__global__ __launch_bounds__(256) void transpose_kernel(
    const float* __restrict__ src, u16* __restrict__ dhi, u16* __restrict__ dlo,
    int R, int C)
{
  __shared__ float tile[64][65];
  src += (size_t)blockIdx.z * R * C;
  dhi += (size_t)blockIdx.z * R * C;
  if (SPLIT) dlo += (size_t)blockIdx.z * R * C;
  int r0 = blockIdx.y*64, c0 = blockIdx.x*64;
  int t = threadIdx.x;
  int lr = t>>2, lc4 = (t&3)*16;
#pragma unroll
  for (int i = 0; i < 4; ++i)
    *reinterpret_cast<f32x4*>(&tile[lr][lc4 + i*4]) =
        *reinterpret_cast<const f32x4*>(src + (size_t)(r0+lr)*C + c0 + lc4 + i*4);
  __syncthreads();
#pragma unroll
  for (int h = 0; h < 2; ++h) {
    int oc = h*32 + (t>>3);
    int ok = (t&7)*8;
    union { u16 a[8]; u32x4 v; } hb, lb;
#pragma unroll
    for (int j = 0; j < 8; ++j) {
      float f = tile[ok+j][oc];
      hb.a[j] = f2bf_bits(f);
      if (SPLIT) lb.a[j] = f2bf_bits(f - bf2f(hb.a[j]));
    }
    *reinterpret_cast<u32x4*>(dhi + (size_t)(c0+oc)*R + r0 + ok) = hb.v;
    if (SPLIT)
      *reinterpret_cast<u32x4*>(dlo + (size_t)(c0+oc)*R + r0 + ok) = lb.v;
  }
}

// fused wq/wk/wv transpose (split): z selects source
__global__ __launch_bounds__(256) void transpose_qkv_kernel(
    const float* __restrict__ wq, const float* __restrict__ wk, const float* __restrict__ wv,
    u16* __restrict__ dhi, u16* __restrict__ dlo)
{
  __shared__ float tile[64][65];
  int z = blockIdx.z;
  const float* src = (z == 0) ? wq : ((z == 1) ? wk : wv);
  dhi += (size_t)z * D_MODEL * D_MODEL;
  dlo += (size_t)z * D_MODEL * D_MODEL;
  int r0 = blockIdx.y*64, c0 = blockIdx.x*64;
  int t = threadIdx.x;
  int lr = t>>2, lc4 = (t&3)*16;
#pragma unroll
  for (int i = 0; i < 4; ++i)
    *reinterpret_cast<f32x4*>(&tile[lr][lc4 + i*4]) =
        *reinterpret_cast<const f32x4*>(src + (size_t)(r0+lr)*D_MODEL + c0 + lc4 + i*4);
  __syncthreads();
#pragma unroll
  for (int h = 0; h < 2; ++h) {
    int oc = h*32 + (t>>3);
    int ok = (t&7)*8;
    union { u16 a[8]; u32x4 v; } hb, lb;
#pragma unroll
    for (int j = 0; j < 8; ++j) {
      float f = tile[ok+j][oc];
      hb.a[j] = f2bf_bits(f);
      lb.a[j] = f2bf_bits(f - bf2f(hb.a[j]));
    }
    *reinterpret_cast<u32x4*>(dhi + (size_t)(c0+oc)*D_MODEL + r0 + ok) = hb.v;
    *reinterpret_cast<u32x4*>(dlo + (size_t)(c0+oc)*D_MODEL + r0 + ok) = lb.v;
  }
}

// ================= V transpose: vbf[tok][h*64+d] -> vT[bh][d][tok] =================
__global__ __launch_bounds__(256) void v_transpose_kernel(
    const u16* __restrict__ vbf, u16* __restrict__ vT)
{
  __shared__ u16 tile[64][72];
  int bh = blockIdx.y, b = bh >> 4, h = bh & 15;
  int t0 = blockIdx.x * 64;
  int t = threadIdx.x;
  int row = t >> 2, c16 = (t & 3) * 16;
  const u16* src = vbf + ((size_t)(b*T_SEQ + t0 + row))*D_MODEL + h*64 + c16;
  *reinterpret_cast<u32x4*>(&tile[row][c16])     = *reinterpret_cast<const u32x4*>(src);
  *reinterpret_cast<u32x4*>(&tile[row][c16 + 8]) = *reinterpret_cast<const u32x4*>(src + 8);
  __syncthreads();
  int d = row, k0 = c16;
  union { u16 a[16]; u32x4 v[2]; } o;
#pragma unroll
  for (int j = 0; j < 16; ++j) o.a[j] = tile[k0 + j][d];
  u16* dst = vT + ((size_t)bh*64 + d)*T_SEQ + t0 + k0;
  *reinterpret_cast<u32x4*>(dst)     = o.v[0];
  *reinterpret_cast<u32x4*>(dst + 8) = o.v[1];
}

// ================= QKV split GEMM: 128x256 tile (A staged once per 2 mats) =================
__global__ __launch_bounds__(256) void qkv_gemm_kernel(
    const u16* __restrict__ Ahi, const u16* __restrict__ Alo,
    const u16* __restrict__ Bhi, const u16* __restrict__ Blo,
    const float* __restrict__ freqs,
    u16* __restrict__ qhi, u16* __restrict__ qlo,
    u16* __restrict__ khi, u16* __restrict__ klo,
    u16* __restrict__ vbf, float* __restrict__ kout, float* __restrict__ vout)
{
  const int K = D_MODEL;
  __shared__ __align__(16) u16 AhS[128*32], AlS[128*32],
                               BhS[256*32], BlS[256*32];   // 48 KB
  int tid = threadIdx.x, lane = tid & 63, wid = tid >> 6;
  int wm = wid >> 1, wn = wid & 1;
  int l15 = lane & 15, l4 = lane >> 4;
  size_t bm = (size_t)blockIdx.y * 128, bn = (size_t)blockIdx.x * 256;
  const u16* Ah0 = Ahi + bm*K;  const u16* Al0 = Alo + bm*K;
  const u16* Bh0 = Bhi + bn*K;  const u16* Bl0 = Blo + bn*K;
  f32x4 acc[4][8] = {};
  for (int kt = 0; kt < K; kt += 32) {
    __syncthreads();
    stage128x32(Ah0, K, kt, AhS, wid, lane);
    stage128x32(Al0, K, kt, AlS, wid, lane);
    stage128x32(Bh0, K, kt, BhS, wid, lane);
    stage128x32(Bh0 + (size_t)128*K, K, kt, BhS + 128*32, wid, lane);
    stage128x32(Bl0, K, kt, BlS, wid, lane);
    stage128x32(Bl0 + (size_t)128*K, K, kt, BlS + 128*32, wid, lane);
    __syncthreads();
    bf16x8 ah[4], al[4];
#pragma unroll
    for (int mi = 0; mi < 4; ++mi) {
      int row = wm*64 + mi*16 + l15;
      ah[mi] = fragLDS(AhS, row, l4, l15);
      al[mi] = fragLDS(AlS, row, l4, l15);
    }
#pragma unroll
    for (int ni = 0; ni < 8; ++ni) {
      int row = wn*128 + ni*16 + l15;
      bf16x8 bh = fragLDS(BhS, row, l4, l15);
      bf16x8 bl = fragLDS(BlS, row, l4, l15);
#pragma unroll
      for (int mi = 0; mi < 4; ++mi) {
        acc[mi][ni] = MFMA16(ah[mi], bh, acc[mi][ni]);
        acc[mi][ni] = MFMA16(ah[mi], bl, acc[mi][ni]);
        acc[mi][ni] = MFMA16(al[mi], bh, acc[mi][ni]);
      }
    }
  }
  // epilogue: mat 0=q,1=k,2=v (uniform per block: 256-wide tile within one mat)
  int mat = (int)(bn >> 10);
  int colbase = (int)(bn & 1023);
  int evenl = !(lane & 1);
#pragma unroll
  for (int mi = 0; mi < 4; ++mi) {
#pragma unroll
    for (int r = 0; r < 4; ++r) {
      int tok = (int)bm + wm*64 + mi*16 + l4*4 + r;
      int t = tok & (T_SEQ - 1);
#pragma unroll
      for (int ni = 0; ni < 8; ++ni) {
        int col = colbase + wn*128 + ni*16 + l15;
        float v = acc[mi][ni][r];
        if (mat == 2) {
          float vp = __shfl_xor(v, 1);
          if (evenl) {
            u32 pk = (u32)cvt_bf16(v) | ((u32)cvt_bf16(vp) << 16);
            *reinterpret_cast<u32*>(vbf + (size_t)tok*D_MODEL + col) = pk;
            f32x2 fv; fv[0] = v; fv[1] = vp;
            *reinterpret_cast<f32x2*>(vout + (size_t)tok*D_MODEL + col) = fv;
          }
        } else {
          int d = col & 63, p = d >> 1;
          f32x2 cs = *reinterpret_cast<const f32x2*>(freqs + ((size_t)t*32 + p)*2);
          float partner = __shfl_xor(v, 1);
          float rot = (d & 1) ? (partner*cs[1] + v*cs[0]) : (v*cs[0] - partner*cs[1]);
          float rotp = __shfl_xor(rot, 1);
          if (evenl) {
            u16 h0 = cvt_bf16(rot), h1 = cvt_bf16(rotp);
            u32 hp = (u32)h0 | ((u32)h1 << 16);
            u32 lp = (u32)cvt_bf16(rot - bf2f(h0)) | ((u32)cvt_bf16(rotp - bf2f(h1)) << 16);
            if (mat == 0) {
              *reinterpret_cast<u32*>(qhi + (size_t)tok*D_MODEL + col) = hp;
              *reinterpret_cast<u32*>(qlo + (size_t)tok*D_MODEL + col) = lp;
            } else {
              *reinterpret_cast<u32*>(khi + (size_t)tok*D_MODEL + col) = hp;
              *reinterpret_cast<u32*>(klo + (size_t)tok*D_MODEL + col) = lp;
              f32x2 fv; fv[0] = rot; fv[1] = rotp;
              *reinterpret_cast<f32x2*>(kout + (size_t)tok*D_MODEL + col) = fv;
            }
          }
        }
      }
    }
  }
}

// ================= WO GEMM: 128x128, x2 = resid + A @ woT =================
__global__ __launch_bounds__(256) void wo_gemm_kernel(
    const u16* __restrict__ A, const u16* __restrict__ Bt,
    const float* __restrict__ resid, float* __restrict__ Cout)
{
  const int K = D_MODEL, N = D_MODEL;
  __shared__ __align__(16) u16 As[128*32], Bs[128*32];
  int tid = threadIdx.x, lane = tid & 63, wid = tid >> 6;
  int wm = wid >> 1, wn = wid & 1;
  int l15 = lane & 15, l4 = lane >> 4;
  size_t bm = (size_t)blockIdx.y * 128, bn = (size_t)blockIdx.x * 128;
  const u16* A0 = A + bm*K;  const u16* B0 = Bt + bn*K;
  f32x4 acc[4][4] = {};
  for (int kt = 0; kt < K; kt += 32) {
    __syncthreads();
    stage128x32(A0, K, kt, As, wid, lane);
    stage128x32(B0, K, kt, Bs, wid, lane);
    __syncthreads();
    bf16x8 a[4];
#pragma unroll
    for (int mi = 0; mi < 4; ++mi)
      a[mi] = fragLDS(As, wm*64 + mi*16 + l15, l4, l15);
#pragma unroll
    for (int ni = 0; ni < 4; ++ni) {
      bf16x8 b = fragLDS(Bs, wn*64 + ni*16 + l15, l4, l15);
#pragma unroll
      for (int mi = 0; mi < 4; ++mi)
        acc[mi][ni] = MFMA16(a[mi], b, acc[mi][ni]);
    }
  }
#pragma unroll
  for (int mi = 0; mi < 4; ++mi)
#pragma unroll
    for (int ni = 0; ni < 4; ++ni)
#pragma unroll
      for (int r = 0; r < 4; ++r) {
        size_t row = bm + wm*64 + mi*16 + l4*4 + r;
        size_t col = bn + wn*64 + ni*16 + l15;
        Cout[row*N + col] = resid[row*N + col] + acc[mi][ni][r];
      }
}

// ================= wg2[d][e] = sum_i wo[d][i]*ffnw[i]*gw[i][e] =================
__global__ __launch_bounds__(64) void wg2_kernel(
    const float* __restrict__ wo, const float* __restrict__ ffnw,
    const float* __restrict__ gw, float* __restrict__ wg2)
{
  int d = blockIdx.x, lane = threadIdx.x;
  const float* wr = wo + (size_t)d * D_MODEL;
  float acc[8] = {0,0,0,0,0,0,0,0};
#pragma unroll
  for (int i = 0; i < 4; ++i) {
    int c = lane*4 + i*256;
    f32x4 wv = *reinterpret_cast<const f32x4*>(wr + c);
    f32x4 fv = *reinterpret_cast<const f32x4*>(ffnw + c);
#pragma unroll
    for (int j = 0; j < 4; ++j) {
      float a = wv[j] * fv[j];
      f32x4 g0 = *reinterpret_cast<const f32x4*>(gw + (size_t)(c + j)*NEXP);
      f32x4 g1 = *reinterpret_cast<const f32x4*>(gw + (size_t)(c + j)*NEXP + 4);
      acc[0]+=a*g0[0]; acc[1]+=a*g0[1]; acc[2]+=a*g0[2]; acc[3]+=a*g0[3];
      acc[4]+=a*g1[0]; acc[5]+=a*g1[1]; acc[6]+=a*g1[2]; acc[7]+=a*g1[3];
    }
  }
#pragma unroll
  for (int off = 32; off >= 1; off >>= 1)
#pragma unroll
    for (int e = 0; e < 8; ++e) acc[e] += __shfl_xor(acc[e], off);
  if (lane == 0) {
#pragma unroll
    for (int e = 0; e < 8; ++e) wg2[(size_t)d*NEXP + e] = acc[e];
  }
}

// ================= Vg[t][h][e] =================
__global__ __launch_bounds__(256) void vg_kernel(
    const float* __restrict__ vf, const float* __restrict__ wg2, float* __restrict__ Vg)
{
  int tok = blockIdx.x * 4 + (threadIdx.x >> 6);
  int lane = threadIdx.x & 63;
  int hh = lane >> 2, part = lane & 3;
  const float* vr = vf + (size_t)tok * D_MODEL + hh*64 + part*16;
  const float* gr = wg2 + (size_t)(hh*64 + part*16) * NEXP;
  float acc[8] = {0,0,0,0,0,0,0,0};
#pragma unroll
  for (int i = 0; i < 4; ++i) {
    f32x4 vv = *reinterpret_cast<const f32x4*>(vr + i*4);
#pragma unroll
    for (int j = 0; j < 4; ++j) {
      float a = vv[j];
      f32x4 g0 = *reinterpret_cast<const f32x4*>(gr + (size_t)(i*4 + j)*NEXP);
      f32x4 g1 = *reinterpret_cast<const f32x4*>(gr + (size_t)(i*4 + j)*NEXP + 4);
      acc[0]+=a*g0[0]; acc[1]+=a*g0[1]; acc[2]+=a*g0[2]; acc[3]+=a*g0[3];
      acc[4]+=a*g1[0]; acc[5]+=a*g1[1]; acc[6]+=a*g1[2]; acc[7]+=a*g1[3];
    }
  }
#pragma unroll
  for (int off = 1; off < 4; off <<= 1)
#pragma unroll
    for (int e = 0; e < 8; ++e) acc[e] += __shfl_xor(acc[e], off);
  if (part == 0) {
#pragma unroll
    for (int e = 0; e < 8; ++e) Vg[((size_t)tok*NHEAD + hh)*NEXP + e] = acc[e];
  }
}

// ================= flash attention v5: K and V both staged via global_load_lds =================
__global__ __launch_bounds__(256) void attn_kernel(
    const u16* __restrict__ Qhi, const u16* __restrict__ Qlo,
    const u16* __restrict__ Khi, const u16* __restrict__ Klo,
    const u16* __restrict__ vT, const float* __restrict__ Vg,
    u16* __restrict__ Ob, float* __restrict__ raw_ao)
{
  int id = blockIdx.x;
  int bh = id & 31, b = bh >> 4, h = bh & 15;
  int rr_ = id >> 8, kk_ = (id >> 5) & 7;
  int qt = (rr_ == 0) ? (31 - kk_) : (rr_ == 1) ? (16 + kk_)
         : (rr_ == 2) ? (15 - kk_) : kk_;
  int tid = threadIdx.x, lane = tid & 63, wid = tid >> 6;
  int l15 = lane & 15, l4 = lane >> 4;

  __shared__ __align__(16) u16 VTs[64*64];
  __shared__ __align__(16) u16 Pl[4][16][72];
  __shared__ float VgS[64][12];
  __shared__ __align__(16) u16 KhS[64*64], KlS[64*64];

  const u16* vTb = vT + ((size_t)bh * 64) * T_SEQ;   // rows d, cols tok

  size_t qoff = ((size_t)(b*T_SEQ + qt*64 + wid*16)) * D_MODEL + h*64;
  bf16x8 qhiF[2], qloF[2];
#pragma unroll
  for (int s = 0; s < 2; ++s) {
    qhiF[s] = frag_b128(Qhi + qoff + (size_t)l15*D_MODEL + s*32 + l4*8);
    qloF[s] = frag_b128(Qlo + qoff + (size_t)l15*D_MODEL + s*32 + l4*8);
  }
  float m_r[4], l_r[4];
  f32x4 racc4[4][2] = {};
  f32x4 oacc[4] = {};
#pragma unroll
  for (int r = 0; r < 4; ++r) { m_r[r] = -1e30f; l_r[r] = 0.f; }

  for (int kt = 0; kt <= qt; ++kt) {
    __syncthreads();
    {
      const u16* kbH = Khi + ((size_t)(b*T_SEQ + kt*64))*D_MODEL + h*64;
      const u16* kbL = Klo + ((size_t)(b*T_SEQ + kt*64))*D_MODEL + h*64;
      stage64x64(kbH, D_MODEL, 0, KhS, wid, lane);
      stage64x64(kbL, D_MODEL, 0, KlS, wid, lane);
      stage64x64(vTb, T_SEQ, kt*64, VTs, wid, lane);   // [64 d][64 keys]
    }
    if (tid < 128) {
      int key = tid >> 1, eh = (tid & 1) * 4;
      const float* gsrc = Vg + ((size_t)(b*T_SEQ + kt*64 + key)*NHEAD + h)*NEXP + eh;
      *reinterpret_cast<f32x4*>(&VgS[key][eh]) = *reinterpret_cast<const f32x4*>(gsrc);
    }
    __syncthreads();

    f32x4 sacc[4] = {};
    __builtin_amdgcn_s_setprio(1);
#pragma unroll
    for (int n = 0; n < 4; ++n) {
#pragma unroll
      for (int s = 0; s < 2; ++s) {
        bf16x8 khiF = fragLDS64(KhS, n*16 + l15, s, l4, l15);
        bf16x8 kloF = fragLDS64(KlS, n*16 + l15, s, l4, l15);
        sacc[n] = MFMA16(qhiF[s], khiF, sacc[n]);
        sacc[n] = MFMA16(qhiF[s], kloF, sacc[n]);
        sacc[n] = MFMA16(qloF[s], khiF, sacc[n]);
      }
    }
    __builtin_amdgcn_s_setprio(0);
#pragma unroll
    for (int n = 0; n < 4; ++n)
#pragma unroll
      for (int r = 0; r < 4; ++r)
        sacc[n][r] *= 0.125f;
    if (kt == qt) {
      int q0 = qt*64 + wid*16 + l4*4;
      int k00 = kt*64 + l15;
#pragma unroll
      for (int n = 0; n < 4; ++n)
#pragma unroll
        for (int r = 0; r < 4; ++r)
          if (k00 + n*16 > q0 + r) sacc[n][r] = -1e30f;
    }
    float rm[4];
#pragma unroll
    for (int r = 0; r < 4; ++r) {
      float v = fmaxf(fmaxf(sacc[0][r], sacc[1][r]), fmaxf(sacc[2][r], sacc[3][r]));
#pragma unroll
      for (int off = 1; off < 16; off <<= 1) v = fmaxf(v, __shfl_xor(v, off));
      rm[r] = v;
    }
    int needp = (rm[0] > m_r[0]+8.f) | (rm[1] > m_r[1]+8.f) |
                (rm[2] > m_r[2]+8.f) | (rm[3] > m_r[3]+8.f);
    if (__any(needp)) {
#pragma unroll
      for (int r = 0; r < 4; ++r) {
        float mn = fmaxf(m_r[r], rm[r]);
        float corr = __expf(m_r[r] - mn);
        m_r[r] = mn;
        l_r[r] *= corr;
        racc4[r][0] *= corr; racc4[r][1] *= corr;
#pragma unroll
        for (int n = 0; n < 4; ++n) oacc[n][r] *= corr;
      }
    }
#pragma unroll
    for (int r = 0; r < 4; ++r) {
      float rs = 0.f;
#pragma unroll
      for (int n = 0; n < 4; ++n) {
        float pp = __expf(sacc[n][r] - m_r[r]);
        sacc[n][r] = pp;
        rs += pp;
      }
#pragma unroll
      for (int off = 1; off < 16; off <<= 1) rs += __shfl_xor(rs, off);
      l_r[r] += rs;
    }
#pragma unroll
    for (int n = 0; n < 4; ++n)
#pragma unroll
      for (int r = 0; r < 4; ++r)
        Pl[wid][l4*4 + r][n*16 + l15] = cvt_bf16(sacc[n][r]);
#pragma unroll
    for (int n = 0; n < 4; ++n) {
      f32x4 g0 = *reinterpret_cast<const f32x4*>(&VgS[n*16 + l15][0]);
      f32x4 g1 = *reinterpret_cast<const f32x4*>(&VgS[n*16 + l15][4]);
#pragma unroll
      for (int r = 0; r < 4; ++r) {
        float pp = sacc[n][r];
        racc4[r][0] += g0 * pp;
        racc4[r][1] += g1 * pp;
      }
    }
    __builtin_amdgcn_s_setprio(1);
#pragma unroll
    for (int s = 0; s < 2; ++s) {
      bf16x8 pa = frag_b128(&Pl[wid][l15][s*32 + l4*8]);
#pragma unroll
      for (int n = 0; n < 4; ++n) {
        bf16x8 vb8 = fragLDS64(VTs, n*16 + l15, s, l4, l15);
        oacc[n] = MFMA16(pa, vb8, oacc[n]);
      }
    }
    __builtin_amdgcn_s_setprio(0);
  }
  float inv[4];
#pragma unroll
  for (int r = 0; r < 4; ++r) inv[r] = 1.0f / l_r[r];
  size_t obase = ((size_t)(b*T_SEQ + qt*64 + wid*16))*D_MODEL + h*64;
#pragma unroll
  for (int n = 0; n < 4; ++n)
#pragma unroll
    for (int r = 0; r < 4; ++r)
      Ob[obase + (size_t)(l4*4 + r)*D_MODEL + n*16 + l15] = cvt_bf16(oacc[n][r]*inv[r]);
  float rv[4][8];
#pragma unroll
  for (int r = 0; r < 4; ++r)
#pragma unroll
    for (int e = 0; e < 8; ++e)
      rv[r][e] = (e < 4) ? racc4[r][0][e] : racc4[r][1][e-4];
#pragma unroll
  for (int off = 1; off < 16; off <<= 1)
#pragma unroll
    for (int r = 0; r < 4; ++r)
#pragma unroll
      for (int e = 0; e < 8; ++e)
        rv[r][e] += __shfl_xor(rv[r][e], off);
  if (l15 == 0) {
#pragma unroll
    for (int r = 0; r < 4; ++r) {
      size_t tokg = (size_t)(b*T_SEQ) + qt*64 + wid*16 + l4*4 + r;
#pragma unroll
      for (int e = 0; e < 8; ++e)
        raw_ao[(tokg*NHEAD + h)*NEXP + e] = rv[r][e]*inv[r];
    }
  }
}

// ================= gate: fp32 logits, top-2 =================
__global__ void zero_counts_kernel(int* counts) {
  if (threadIdx.x < NEXP) counts[threadIdx.x] = 0;
}

__global__ __launch_bounds__(256) void gate2_kernel(
    const float* __restrict__ x, const float* __restrict__ x2,
    const float* __restrict__ ffnw, const float* __restrict__ gw,
    const float* __restrict__ raw_ao,
    int* __restrict__ gidx, float* __restrict__ gwt, int* __restrict__ counts)
{
  int tok = blockIdx.x * 4 + (threadIdx.x >> 6);
  int lane = threadIdx.x & 63;
  const float* xr = x + (size_t)tok * D_MODEL;
  const float* x2r = x2 + (size_t)tok * D_MODEL;
  float ss = 0.f;
  float lg[8] = {0,0,0,0,0,0,0,0};
#pragma unroll
  for (int i = 0; i < 4; ++i) {
    int d = lane*4 + i*256;
    f32x4 xv = *reinterpret_cast<const f32x4*>(xr + d);
    f32x4 x2v = *reinterpret_cast<const f32x4*>(x2r + d);
    f32x4 wv = *reinterpret_cast<const f32x4*>(ffnw + d);
    ss += x2v[0]*x2v[0] + x2v[1]*x2v[1] + x2v[2]*x2v[2] + x2v[3]*x2v[3];
#pragma unroll
    for (int j = 0; j < 4; ++j) {
      float a = xv[j]*wv[j];
      f32x4 g0 = *reinterpret_cast<const f32x4*>(gw + (size_t)(d + j)*NEXP);
      f32x4 g1 = *reinterpret_cast<const f32x4*>(gw + (size_t)(d + j)*NEXP + 4);
      lg[0]+=a*g0[0]; lg[1]+=a*g0[1]; lg[2]+=a*g0[2]; lg[3]+=a*g0[3];
      lg[4]+=a*g1[0]; lg[5]+=a*g1[1]; lg[6]+=a*g1[2]; lg[7]+=a*g1[3];
    }
  }
#pragma unroll
  for (int off = 1; off < 64; off <<= 1) {
    ss += __shfl_xor(ss, off);
#pragma unroll
    for (int e = 0; e < 8; ++e) lg[e] += __shfl_xor(lg[e], off);
  }
  float ah[8] = {0,0,0,0,0,0,0,0};
  if (lane < 16) {
    const float* ar = raw_ao + ((size_t)tok*NHEAD + lane)*NEXP;
#pragma unroll
    for (int e = 0; e < 8; ++e) ah[e] = ar[e];
  }
#pragma unroll
  for (int off = 1; off < 16; off <<= 1)
#pragma unroll
    for (int e = 0; e < 8; ++e) ah[e] += __shfl_xor(ah[e], off);
  if (lane == 0) {
    float rms = rsqrtf(ss*(1.0f/D_MODEL) + 1e-6f);
    float lo_[8], pp[8];
    float mx = -1e30f;
#pragma unroll
    for (int e = 0; e < 8; ++e) { lo_[e] = (lg[e] + ah[e]) * rms; mx = fmaxf(mx, lo_[e]); }
    float sum = 0.f;
#pragma unroll
    for (int e = 0; e < 8; ++e) { pp[e] = __expf(lo_[e] - mx); sum += pp[e]; }
    float isum = 1.0f/sum;
#pragma unroll
    for (int e = 0; e < 8; ++e) pp[e] *= isum;
    int i0 = 0;
    for (int e = 1; e < 8; ++e) if (pp[e] > pp[i0]) i0 = e;
    int i1 = (i0 == 0) ? 1 : 0;
    for (int e = 0; e < 8; ++e) if (e != i0 && pp[e] > pp[i1]) i1 = e;
    float v0 = pp[i0], v1 = pp[i1];
    float wnorm = 1.0f/(v0 + v1 + 1e-8f);
    gidx[2*tok] = i0; gidx[2*tok+1] = i1;
    gwt[2*tok] = v0*wnorm; gwt[2*tok+1] = v1*wnorm;
    atomicAdd(&counts[i0], 1); atomicAdd(&counts[i1], 1);
  }
}

// ================= routing =================
__global__ __launch_bounds__(256) void scan_kernel(
    const int* __restrict__ counts, int* __restrict__ base, int* __restrict__ fill,
    int* __restrict__ blk_expert, int* __restrict__ perm_token)
{
  if (threadIdx.x == 0) {
    int b = 0, blk = 0;
    for (int e = 0; e < NEXP; ++e) {
      base[e] = b;
      fill[e] = 0;
      int nb = (counts[e] + 127) >> 7;
      for (int i = 0; i < nb; ++i) blk_expert[blk++] = e;
      b += nb << 7;
    }
    for (; blk < MAXBLK; ++blk) blk_expert[blk] = -1;
  }
  for (int i = threadIdx.x; i < SLOTS; i += 256) perm_token[i] = -1;
}

__global__ __launch_bounds__(256) void scatter_kernel(
    const int* __restrict__ gidx, const int* __restrict__ base, int* __restrict__ fill,
    int* __restrict__ perm_token, int* __restrict__ tok_slot)
{
  int t = blockIdx.x * 256 + threadIdx.x;
  if (t >= NTOK) return;
#pragma unroll
  for (int r = 0; r < 2; ++r) {
    int e = gidx[2*t + r];
    int pos = base[e] + atomicAdd(&fill[e], 1);
    perm_token[pos] = t;
    tok_slot[2*t + r] = pos;
  }
}

// ================= MoE GEMM1: BN=64, BK=64 =================
__global__ __launch_bounds__(256) void moe_gemm1_kernel(
    const u16* __restrict__ Ah, const u16* __restrict__ W1t, const u16* __restrict__ W3t,
    const int* __restrict__ perm_token, const int* __restrict__ blk_expert,
    u16* __restrict__ tbuf)
{
  int mb = blockIdx.y;
  int e = blk_expert[mb];
  if (e < 0) return;
  const int K = D_MODEL;
  __shared__ __align__(16) u16 As[128*64], B1s[64*64], B3s[64*64];  // 32 KB
  int tid = threadIdx.x, lane = tid & 63, wid = tid >> 6;
  int wm = wid >> 1, wn = wid & 1;
  int l15 = lane & 15, l4 = lane >> 4;
  size_t bn = (size_t)blockIdx.x * 64;
  const u16* w1e = W1t + (size_t)e * HID_DIM * D_MODEL + bn*K;
  const u16* w3e = W3t + (size_t)e * HID_DIM * D_MODEL + bn*K;
  int rl = lane >> 3, cc = lane & 7;
  int tokA[4];
#pragma unroll
  for (int g = 0; g < 4; ++g) {
    int row = wid*32 + g*8 + rl;
    int t = perm_token[mb*128 + row];
    tokA[g] = t < 0 ? 0 : t;
  }
  f32x4 acc1[4][2] = {}, acc3[4][2] = {};
  for (int kt = 0; kt < K; kt += 64) {
    __syncthreads();
#pragma unroll
    for (int g = 0; g < 4; ++g) {
      int row = wid*32 + g*8 + rl;
      int chunk = cc ^ (row & 7);
      gload16(Ah + (size_t)tokA[g]*K + kt + chunk*8, As + (size_t)(wid*32 + g*8)*64);
    }
    stage64x64(w1e, K, kt, B1s, wid, lane);
    stage64x64(w3e, K, kt, B3s, wid, lane);
    __syncthreads();
#pragma unroll
    for (int s = 0; s < 2; ++s) {
      bf16x8 a[4];
#pragma unroll
      for (int mi = 0; mi < 4; ++mi)
        a[mi] = fragLDS64(As, wm*64 + mi*16 + l15, s, l4, l15);
#pragma unroll
      for (int ni = 0; ni < 2; ++ni) {
        int row = wn*32 + ni*16 + l15;
        bf16x8 b1 = fragLDS64(B1s, row, s, l4, l15);
        bf16x8 b3 = fragLDS64(B3s, row, s, l4, l15);
#pragma unroll
        for (int mi = 0; mi < 4; ++mi) {
          acc1[mi][ni] = MFMA16(a[mi], b1, acc1[mi][ni]);
          acc3[mi][ni] = MFMA16(a[mi], b3, acc3[mi][ni]);
        }
      }
    }
  }
  int evenl = !(lane & 1);
#pragma unroll
  for (int mi = 0; mi < 4; ++mi)
#pragma unroll
    for (int ni = 0; ni < 2; ++ni)
#pragma unroll
      for (int r = 0; r < 4; ++r) {
        size_t slot = (size_t)mb*128 + wm*64 + mi*16 + l4*4 + r;
        size_t col = bn + wn*32 + ni*16 + l15;
        float h1 = acc1[mi][ni][r], h3 = acc3[mi][ni][r];
        float t = h1 * __builtin_amdgcn_rcpf(1.0f + __expf(-h1)) * h3;
        float tp = __shfl_xor(t, 1);
        if (evenl) {
          u32 pk = (u32)cvt_bf16(t) | ((u32)cvt_bf16(tp) << 16);
          *reinterpret_cast<u32*>(tbuf + slot*HID_DIM + col) = pk;
        }
      }
}

// ================= MoE GEMM2: BK=32: y = t @ w2T =================
__global__ __launch_bounds__(256) void moe_gemm2_kernel(
    const u16* __restrict__ tbuf, const u16* __restrict__ W2t,
    const int* __restrict__ blk_expert, u16* __restrict__ ybuf)
{
  int mb = blockIdx.y;
  int e = blk_expert[mb];
  if (e < 0) return;
  const int K = HID_DIM, N = D_MODEL;
  __shared__ __align__(16) u16 As[128*32], Bs[128*32];   // 16 KB
  int tid = threadIdx.x, lane = tid & 63, wid = tid >> 6;
  int wm = wid >> 1, wn = wid & 1;
  int l15 = lane & 15, l4 = lane >> 4;
  size_t bm = (size_t)mb * 128, bn = (size_t)blockIdx.x * 128;
  const u16* A0 = tbuf + bm*K;
  const u16* B0 = W2t + (size_t)e * D_MODEL * HID_DIM + bn*K;
  f32x4 acc[4][4] = {};
  for (int kt = 0; kt < K; kt += 32) {
    __syncthreads();
    stage128x32(A0, K, kt, As, wid, lane);
    stage128x32(B0, K, kt, Bs, wid, lane);
    __syncthreads();
    bf16x8 a[4];
#pragma unroll
    for (int mi = 0; mi < 4; ++mi)
      a[mi] = fragLDS(As, wm*64 + mi*16 + l15, l4, l15);
#pragma unroll
    for (int ni = 0; ni < 4; ++ni) {
      bf16x8 b = fragLDS(Bs, wn*64 + ni*16 + l15, l4, l15);
#pragma unroll
      for (int mi = 0; mi < 4; ++mi)
        acc[mi][ni] = MFMA16(a[mi], b, acc[mi][ni]);
    }
  }
  int evenl = !(lane & 1);
#pragma unroll
  for (int mi = 0; mi < 4; ++mi)
#pragma unroll
    for (int ni = 0; ni < 4; ++ni)
#pragma unroll
      for (int r = 0; r < 4; ++r) {
        float v = acc[mi][ni][r];
        float vp = __shfl_xor(v, 1);
        if (evenl) {
          size_t slot = bm + wm*64 + mi*16 + l4*4 + r;
          size_t col = bn + wn*64 + ni*16 + l15;
          u32 pk = (u32)cvt_bf16(v) | ((u32)cvt_bf16(vp) << 16);
          *reinterpret_cast<u32*>(ybuf + slot*N + col) = pk;
        }
      }
}

// ================= combine =================
__global__ __launch_bounds__(256) void combine_kernel(
    const float* __restrict__ x2, const u16* __restrict__ ybuf,
    const int* __restrict__ tok_slot, const float* __restrict__ gwt,
    float* __restrict__ xout)
{
  int t = blockIdx.x;
  int c = threadIdx.x * 4;
  int s0 = tok_slot[2*t], s1 = tok_slot[2*t+1];
  float w0 = gwt[2*t], w1 = gwt[2*t+1];
  f32x4 xv = *reinterpret_cast<const f32x4*>(x2 + (size_t)t * D_MODEL + c);
  const u16* y0 = ybuf + (size_t)s0 * D_MODEL + c;
  const u16* y1 = ybuf + (size_t)s1 * D_MODEL + c;
  f32x4 o;
#pragma unroll
  for (int j = 0; j < 4; ++j)
    o[j] = xv[j] + w0 * bf2f(y0[j]) + w1 * bf2f(y1[j]);
  *reinterpret_cast<f32x4*>(xout + (size_t)t * D_MODEL + c) = o;
}

// ================= host launch =================
extern "C" void kernel_launch(void* const* d_in, const int* in_sizes, int n_in,
                              void* d_out, int out_size, void* d_ws, size_t ws_size,
                              hipStream_t stream)
{
  (void)in_sizes; (void)n_in; (void)out_size; (void)ws_size;
  const float* x     = (const float*)d_in[0];
  const float* freqs = (const float*)d_in[1];
  const float* attnw = (const float*)d_in[3];
  const float* ffnw  = (const float*)d_in[4];
  const float* wq    = (const float*)d_in[5];
  const float* wk    = (const float*)d_in[6];
  const float* wv    = (const float*)d_in[7];
  const float* wo    = (const float*)d_in[8];
  const float* gw    = (const float*)d_in[9];
  const float* w1    = (const float*)d_in[10];
  const float* w2    = (const float*)d_in[11];
  const float* w3    = (const float*)d_in[12];
  float* xout = (float*)d_out;
  float* kout = xout + (size_t)NTOK * D_MODEL;
  float* vout = kout + (size_t)NTOK * D_MODEL;

  const size_t PLANE = (size_t)NTOK * D_MODEL * 2;      // 8,388,608
  const size_t QKVT  = (size_t)3 * D_MODEL * D_MODEL * 2; // 6,291,456
  const size_t TBUFB = (size_t)SLOTS * HID_DIM * 2;     // 37,748,736
  const size_t WEXP  = (size_t)NEXP * D_MODEL * HID_DIM * 2; // 33,554,432
  char* base = (char*)d_ws;
  // region P: [0, 37.75M) : hhi|hlo|wqkvT planes / woT ; later tbuf
  u16* hhi      = (u16*)(base);
  u16* hlo      = (u16*)(base + PLANE);
  u16* wqkvT_hi = (u16*)(base + 2*PLANE);
  u16* wqkvT_lo = (u16*)(base + 2*PLANE + QKVT);
  u16* woT      = (u16*)(base + 2*PLANE);               // after qkv gemm
  u16* tbuf     = (u16*)(base);                          // moe1..moe2
  // region Q: q/k planes + vbf ; later w1T ; later ybuf
  char* Qb = base + TBUFB;
  u16* qhi = (u16*)(Qb);
  u16* qlo = (u16*)(Qb + PLANE);
  u16* khi = (u16*)(Qb + 2*PLANE);
  u16* klo = (u16*)(Qb + 3*PLANE);
  u16* vbf = (u16*)(Qb + 4*PLANE);
  u16* w1T  = (u16*)(Qb);                                // after attn
  u16* ybuf = (u16*)(Qb);                                // after moe1
  // region S: aobf | vT ; later w3T ; later w2T
  char* Sb = Qb + 5*PLANE;
  u16* aobf = (u16*)(Sb);
  u16* vT   = (u16*)(Sb + PLANE);                        // [32 bh][64 d][2048 tok]
  u16* w3T  = (u16*)(Sb);                                // after wo gemm (aobf+vT dead)
  u16* w2T  = (u16*)(Sb);                                // after moe1
  // region T: hf ; region X: x2
  char* Tb = Sb + WEXP;
  u16* hf = (u16*)(Tb);
  float* x2 = (float*)(Tb + PLANE);
  // smalls
  char* p = Tb + PLANE + (size_t)NTOK * D_MODEL * 4;
  float* wg2    = (float*)p;  p += 32768;
  float* Vg     = (float*)p;  p += (size_t)NTOK*NHEAD*NEXP*4;
  float* raw_ao = (float*)p;  p += (size_t)NTOK*NHEAD*NEXP*4;
  int*   gidx   = (int*)p;    p += 32768;
  float* gwt    = (float*)p;  p += 32768;
  int*   tok_slot = (int*)p;  p += 32768;
  int*   perm   = (int*)p;    p += SLOTS*4;
  int*   counts = (int*)p;
  int*   base_  = counts + 8;
  int*   fill_  = counts + 16;
  int*   blk_e  = counts + 24;

  dim3 blk(256);
  // 1. norms + small precomputes
  rmsnorm_kernel<1><<<NTOK, blk, 0, stream>>>(x, attnw, hhi, hlo);
  wg2_kernel<<<D_MODEL, 64, 0, stream>>>(wo, ffnw, gw, wg2);
  zero_counts_kernel<<<1, 64, 0, stream>>>(counts);
  // 2. fused transpose+split wq/wk/wv (one launch, z=3)
  dim3 tg3(16, 16, 3);
  transpose_qkv_kernel<<<tg3, blk, 0, stream>>>(wq, wk, wv, wqkvT_hi, wqkvT_lo);
  // 3. fused QKV split-GEMM + rope epilogue (BN=256: A staged once per 2x cols)
  dim3 gqkv(12, 32);
  qkv_gemm_kernel<<<gqkv, blk, 0, stream>>>(hhi, hlo, wqkvT_hi, wqkvT_lo, freqs,
                                            qhi, qlo, khi, klo, vbf, kout, vout);
  // 4. V transpose, woT, Vg
  dim3 gvt(T_SEQ/64, 32);
  v_transpose_kernel<<<gvt, blk, 0, stream>>>(vbf, vT);
  dim3 tg(16, 16);
  transpose_kernel<0><<<tg, blk, 0, stream>>>(wo, woT, nullptr, D_MODEL, D_MODEL);
  vg_kernel<<<NTOK/4, blk, 0, stream>>>(vout, wg2, Vg);
  // 5. attention: 1024 blocks, zig-zag balanced qt, K+V staged in LDS
  attn_kernel<<<dim3(1024), blk, 0, stream>>>(qhi, qlo, khi, klo, vT, Vg, aobf, raw_ao);
  // 6. w1T, WO gemm
  dim3 tw13(HID_DIM/64, D_MODEL/64, NEXP);
  transpose_kernel<0><<<tw13, blk, 0, stream>>>(w1, w1T, nullptr, D_MODEL, HID_DIM);
  dim3 g88(D_MODEL/128, NTOK/128);
  wo_gemm_kernel<<<g88, blk, 0, stream>>>(aobf, woT, x, x2);
  // 7. w3T, norm, gate, routing
  transpose_kernel<0><<<tw13, blk, 0, stream>>>(w3, w3T, nullptr, D_MODEL, HID_DIM);
  rmsnorm_kernel<0><<<NTOK, blk, 0, stream>>>(x2, ffnw, hf, nullptr);
  gate2_kernel<<<NTOK/4, blk, 0, stream>>>(x, x2, ffnw, gw, raw_ao, gidx, gwt, counts);
  scan_kernel<<<1, blk, 0, stream>>>(counts, base_, fill_, blk_e, perm);
  scatter_kernel<<<NTOK/256, blk, 0, stream>>>(gidx, base_, fill_, perm, tok_slot);
  // 8. MoE gemm1: BN=64 grid
  dim3 g1(HID_DIM/64, MAXBLK);
  moe_gemm1_kernel<<<g1, blk, 0, stream>>>(hf, w1T, w3T, perm, blk_e, tbuf);
  // 9. w2T, gemm2
  dim3 tw2(D_MODEL/64, HID_DIM/64, NEXP);
  transpose_kernel<0><<<tw2, blk, 0, stream>>>(w2, w2T, nullptr, HID_DIM, D_MODEL);
  dim3 g2(D_MODEL/128, MAXBLK);
  moe_gemm2_kernel<<<g2, blk, 0, stream>>>(tbuf, w2T, blk_e, ybuf);
  // 10. combine
  combine_kernel<<<NTOK, blk, 0, stream>>>(x2, ybuf, tok_slot, gwt, xout);
}

// Round 14
// 799.115 us; speedup vs baseline: 1.0879x; 1.0879x over previous
//
#include <hip/hip_runtime.h>

#define T_SEQ   2048
#define D_MODEL 1024
#define NHEAD   16
#define NEXP    8
#define HID_DIM 2048
#define NTOK    4096
#define MAXBLK  72
#define SLOTS   9216

typedef unsigned short u16;
typedef unsigned int   u32;
typedef __bf16 bf16_t;
typedef bf16_t bf16x8 __attribute__((ext_vector_type(8)));
typedef float  f32x4  __attribute__((ext_vector_type(4)));
typedef float  f32x2  __attribute__((ext_vector_type(2)));
typedef u32    u32x4  __attribute__((ext_vector_type(4)));

typedef __attribute__((address_space(1))) const void* gptr1_t;
typedef __attribute__((address_space(3))) void*       lptr3_t;

__device__ __forceinline__ u16 f2bf_bits(float f) {
  u32 u = __builtin_bit_cast(u32, f);
  u += 0x7FFFu + ((u >> 16) & 1u);
  return (u16)(u >> 16);
}
__device__ __forceinline__ float bf2f(u16 s) {
  return __builtin_bit_cast(float, (u32)s << 16);
}
__device__ __forceinline__ bf16x8 frag_b128(const u16* p) {
  return *reinterpret_cast<const bf16x8*>(p);
}
__device__ __forceinline__ u16 cvt_bf16(float f) {
  return __builtin_bit_cast(u16, (__bf16)f);
}
#define MFMA16(a,b,c) __builtin_amdgcn_mfma_f32_16x16x32_bf16((a),(b),(c),0,0,0)

// ---- async global->LDS, 16B per lane, wave-uniform LDS base ----
__device__ __forceinline__ void gload16(const void* g, void* l) {
  __builtin_amdgcn_global_load_lds((gptr1_t)g, (lptr3_t)l, 16, 0, 0);
}

// ---- BK=32 tile staging: [128][32]-u16, source-side XOR swizzle ----
__device__ __forceinline__ void stage128x32(const u16* gbase, size_t ldk, int kt,
                                            u16* lds, int wid, int lane) {
  int rl = lane >> 2, cc = lane & 3;
#pragma unroll
  for (int h = 0; h < 2; ++h) {
    int row = wid*32 + h*16 + rl;
    int chunk = cc ^ ((row >> 1) & 3);
    gload16(gbase + (size_t)row*ldk + kt + chunk*8, lds + (size_t)(wid*32 + h*16)*32);
  }
}
__device__ __forceinline__ bf16x8 fragLDS(const u16* lds, int row, int l4, int l15) {
  int chunk = l4 ^ ((l15 >> 1) & 3);
  return frag_b128(lds + row*32 + chunk*8);
}

// ---- BK=64 tile staging: [128][64]-u16, chunk = cc ^ (row&7) ----
__device__ __forceinline__ void stage128x64(const u16* gbase, size_t ldk, int kt,
                                            u16* lds, int wid, int lane) {
  int rl = lane >> 3, cc = lane & 7;
#pragma unroll
  for (int g = 0; g < 4; ++g) {
    int row = wid*32 + g*8 + rl;
    int chunk = cc ^ (row & 7);
    gload16(gbase + (size_t)row*ldk + kt + chunk*8, lds + (size_t)(wid*32 + g*8)*64);
  }
}
// ---- BK=64, 64-row tile staging: [64][64]-u16 ----
__device__ __forceinline__ void stage64x64(const u16* gbase, size_t ldk, int kt,
                                           u16* lds, int wid, int lane) {
  int rl = lane >> 3, cc = lane & 7;
#pragma unroll
  for (int g = 0; g < 2; ++g) {
    int row = wid*16 + g*8 + rl;
    int chunk = cc ^ (row & 7);
    gload16(gbase + (size_t)row*ldk + kt + chunk*8, lds + (size_t)(wid*16 + g*8)*64);
  }
}
__device__ __forceinline__ bf16x8 fragLDS64(const u16* lds, int row, int s, int l4, int l15) {
  int chunk = (s*4 + l4) ^ (l15 & 7);   // row&7 == l15&7 (row = 16m + l15)
  return frag_b128(lds + row*64 + chunk*8);
}

// ================= rmsnorm (optionally split hi/lo bf16) =================
template<int SPLIT>
__global__ __launch_bounds__(256) void rmsnorm_kernel(
    const float* __restrict__ x, const float* __restrict__ w,
    u16* __restrict__ hi, u16* __restrict__ lo)
{
  int row = blockIdx.x, tid = threadIdx.x;
  const float* xr = x + (size_t)row * D_MODEL;
  f32x4 v = *reinterpret_cast<const f32x4*>(xr + tid * 4);
  float ss = v[0]*v[0] + v[1]*v[1] + v[2]*v[2] + v[3]*v[3];
#pragma unroll
  for (int off = 32; off >= 1; off >>= 1) ss += __shfl_xor(ss, off);
  __shared__ float part[4];
  if ((tid & 63) == 0) part[tid >> 6] = ss;
  __syncthreads();
  float rms = rsqrtf((part[0]+part[1]+part[2]+part[3]) * (1.0f/D_MODEL) + 1e-6f);
  f32x4 wv = *reinterpret_cast<const f32x4*>(w + tid * 4);
  u32 hw0=0, hw1=0, lw0=0, lw1=0;
#pragma unroll
  for (int j = 0; j < 4; ++j) {
    float f = v[j] * rms * wv[j];
    u16 hb = f2bf_bits(f);
    if (j < 2) hw0 |= (u32)hb << (16*j); else hw1 |= (u32)hb << (16*(j-2));
    if (SPLIT) {
      u16 lb = f2bf_bits(f - bf2f(hb));
      if (j < 2) lw0 |= (u32)lb << (16*j); else lw1 |= (u32)lb << (16*(j-2));
    }
  }
  u32* hp = reinterpret_cast<u32*>(hi + (size_t)row * D_MODEL + tid * 4);
  hp[0] = hw0; hp[1] = hw1;
  if (SPLIT) {
    u32* lp = reinterpret_cast<u32*>(lo + (size_t)row * D_MODEL + tid * 4);
    lp[0] = lw0; lp[1] = lw1;
  }
}

// ================= weight prep: transpose f32 [R][C] -> bf16 [C][R] =================
template<int SPLIT>
__global__ __launch_bounds__(256) void transpose_kernel(
    const float* __restrict__ src, u16* __restrict__ dhi, u16* __restrict__ dlo,
    int R, int C)
{
  __shared__ float tile[64][65];
  src += (size_t)blockIdx.z * R * C;
  dhi += (size_t)blockIdx.z * R * C;
  if (SPLIT) dlo += (size_t)blockIdx.z * R * C;
  int r0 = blockIdx.y*64, c0 = blockIdx.x*64;
  int t = threadIdx.x;
  int lr = t>>2, lc4 = (t&3)*16;
#pragma unroll
  for (int i = 0; i < 4; ++i)
    *reinterpret_cast<f32x4*>(&tile[lr][lc4 + i*4]) =
        *reinterpret_cast<const f32x4*>(src + (size_t)(r0+lr)*C + c0 + lc4 + i*4);
  __syncthreads();
#pragma unroll
  for (int h = 0; h < 2; ++h) {
    int oc = h*32 + (t>>3);
    int ok = (t&7)*8;
    union { u16 a[8]; u32x4 v; } hb, lb;
#pragma unroll
    for (int j = 0; j < 8; ++j) {
      float f = tile[ok+j][oc];
      hb.a[j] = f2bf_bits(f);
      if (SPLIT) lb.a[j] = f2bf_bits(f - bf2f(hb.a[j]));
    }
    *reinterpret_cast<u32x4*>(dhi + (size_t)(c0+oc)*R + r0 + ok) = hb.v;
    if (SPLIT)
      *reinterpret_cast<u32x4*>(dlo + (size_t)(c0+oc)*R + r0 + ok) = lb.v;
  }
}

// fused wq/wk/wv transpose (split): z selects source
__global__ __launch_bounds__(256) void transpose_qkv_kernel(
    const float* __restrict__ wq, const float* __restrict__ wk, const float* __restrict__ wv,
    u16* __restrict__ dhi, u16* __restrict__ dlo)
{
  __shared__ float tile[64][65];
  int z = blockIdx.z;
  const float* src = (z == 0) ? wq : ((z == 1) ? wk : wv);
  dhi += (size_t)z * D_MODEL * D_MODEL;
  dlo += (size_t)z * D_MODEL * D_MODEL;
  int r0 = blockIdx.y*64, c0 = blockIdx.x*64;
  int t = threadIdx.x;
  int lr = t>>2, lc4 = (t&3)*16;
#pragma unroll
  for (int i = 0; i < 4; ++i)
    *reinterpret_cast<f32x4*>(&tile[lr][lc4 + i*4]) =
        *reinterpret_cast<const f32x4*>(src + (size_t)(r0+lr)*D_MODEL + c0 + lc4 + i*4);
  __syncthreads();
#pragma unroll
  for (int h = 0; h < 2; ++h) {
    int oc = h*32 + (t>>3);
    int ok = (t&7)*8;
    union { u16 a[8]; u32x4 v; } hb, lb;
#pragma unroll
    for (int j = 0; j < 8; ++j) {
      float f = tile[ok+j][oc];
      hb.a[j] = f2bf_bits(f);
      lb.a[j] = f2bf_bits(f - bf2f(hb.a[j]));
    }
    *reinterpret_cast<u32x4*>(dhi + (size_t)(c0+oc)*D_MODEL + r0 + ok) = hb.v;
    *reinterpret_cast<u32x4*>(dlo + (size_t)(c0+oc)*D_MODEL + r0 + ok) = lb.v;
  }
}

// ================= V transpose: vbf[tok][h*64+d] -> vT[bh][d][tok] =================
__global__ __launch_bounds__(256) void v_transpose_kernel(
    const u16* __restrict__ vbf, u16* __restrict__ vT)
{
  __shared__ u16 tile[64][72];
  int bh = blockIdx.y, b = bh >> 4, h = bh & 15;
  int t0 = blockIdx.x * 64;
  int t = threadIdx.x;
  int row = t >> 2, c16 = (t & 3) * 16;
  const u16* src = vbf + ((size_t)(b*T_SEQ + t0 + row))*D_MODEL + h*64 + c16;
  *reinterpret_cast<u32x4*>(&tile[row][c16])     = *reinterpret_cast<const u32x4*>(src);
  *reinterpret_cast<u32x4*>(&tile[row][c16 + 8]) = *reinterpret_cast<const u32x4*>(src + 8);
  __syncthreads();
  int d = row, k0 = c16;
  union { u16 a[16]; u32x4 v[2]; } o;
#pragma unroll
  for (int j = 0; j < 16; ++j) o.a[j] = tile[k0 + j][d];
  u16* dst = vT + ((size_t)bh*64 + d)*T_SEQ + t0 + k0;
  *reinterpret_cast<u32x4*>(dst)     = o.v[0];
  *reinterpret_cast<u32x4*>(dst + 8) = o.v[1];
}

// ================= QKV split GEMM, double-buffered (round-11 form) =================
__global__ __launch_bounds__(256) void qkv_gemm_kernel(
    const u16* __restrict__ Ahi, const u16* __restrict__ Alo,
    const u16* __restrict__ Bhi, const u16* __restrict__ Blo,
    const float* __restrict__ freqs,
    u16* __restrict__ qhi, u16* __restrict__ qlo,
    u16* __restrict__ khi, u16* __restrict__ klo,
    u16* __restrict__ vbf, float* __restrict__ kout, float* __restrict__ vout)
{
  const int K = D_MODEL;
  __shared__ __align__(16) u16 AhS[2][128*32], AlS[2][128*32],
                               BhS[2][128*32], BlS[2][128*32];   // 64 KB
  int tid = threadIdx.x, lane = tid & 63, wid = tid >> 6;
  int wm = wid >> 1, wn = wid & 1;
  int l15 = lane & 15, l4 = lane >> 4;
  size_t bm = (size_t)blockIdx.y * 128, bn = (size_t)blockIdx.x * 128;
  const u16* Ah0 = Ahi + bm*K;  const u16* Al0 = Alo + bm*K;
  const u16* Bh0 = Bhi + bn*K;  const u16* Bl0 = Blo + bn*K;
  f32x4 acc[4][4] = {};
  stage128x32(Ah0, K, 0, AhS[0], wid, lane);
  stage128x32(Al0, K, 0, AlS[0], wid, lane);
  stage128x32(Bh0, K, 0, BhS[0], wid, lane);
  stage128x32(Bl0, K, 0, BlS[0], wid, lane);
  __syncthreads();
  int cur = 0;
  for (int kt = 0; kt < K; kt += 32) {
    if (kt + 32 < K) {
      int nxt = cur ^ 1;
      stage128x32(Ah0, K, kt + 32, AhS[nxt], wid, lane);
      stage128x32(Al0, K, kt + 32, AlS[nxt], wid, lane);
      stage128x32(Bh0, K, kt + 32, BhS[nxt], wid, lane);
      stage128x32(Bl0, K, kt + 32, BlS[nxt], wid, lane);
    }
    bf16x8 ah[4], al[4];
#pragma unroll
    for (int mi = 0; mi < 4; ++mi) {
      int row = wm*64 + mi*16 + l15;
      ah[mi] = fragLDS(AhS[cur], row, l4, l15);
      al[mi] = fragLDS(AlS[cur], row, l4, l15);
    }
#pragma unroll
    for (int ni = 0; ni < 4; ++ni) {
      int row = wn*64 + ni*16 + l15;
      bf16x8 bh = fragLDS(BhS[cur], row, l4, l15);
      bf16x8 bl = fragLDS(BlS[cur], row, l4, l15);
#pragma unroll
      for (int mi = 0; mi < 4; ++mi) {
        acc[mi][ni] = MFMA16(ah[mi], bh, acc[mi][ni]);
        acc[mi][ni] = MFMA16(ah[mi], bl, acc[mi][ni]);
        acc[mi][ni] = MFMA16(al[mi], bh, acc[mi][ni]);
      }
    }
    __syncthreads();
    cur ^= 1;
  }
  int mat = (int)(bn >> 10);
  int colbase = (int)(bn & 1023);
  int evenl = !(lane & 1);
#pragma unroll
  for (int mi = 0; mi < 4; ++mi) {
#pragma unroll
    for (int r = 0; r < 4; ++r) {
      int tok = (int)bm + wm*64 + mi*16 + l4*4 + r;
      int t = tok & (T_SEQ - 1);
#pragma unroll
      for (int ni = 0; ni < 4; ++ni) {
        int col = colbase + wn*64 + ni*16 + l15;
        float v = acc[mi][ni][r];
        if (mat == 2) {
          float vp = __shfl_xor(v, 1);
          if (evenl) {
            u32 pk = (u32)cvt_bf16(v) | ((u32)cvt_bf16(vp) << 16);
            *reinterpret_cast<u32*>(vbf + (size_t)tok*D_MODEL + col) = pk;
            f32x2 fv; fv[0] = v; fv[1] = vp;
            *reinterpret_cast<f32x2*>(vout + (size_t)tok*D_MODEL + col) = fv;
          }
        } else {
          int d = col & 63, p = d >> 1;
          f32x2 cs = *reinterpret_cast<const f32x2*>(freqs + ((size_t)t*32 + p)*2);
          float partner = __shfl_xor(v, 1);
          float rot = (d & 1) ? (partner*cs[1] + v*cs[0]) : (v*cs[0] - partner*cs[1]);
          float rotp = __shfl_xor(rot, 1);
          if (evenl) {
            u16 h0 = cvt_bf16(rot), h1 = cvt_bf16(rotp);
            u32 hp = (u32)h0 | ((u32)h1 << 16);
            u32 lp = (u32)cvt_bf16(rot - bf2f(h0)) | ((u32)cvt_bf16(rotp - bf2f(h1)) << 16);
            if (mat == 0) {
              *reinterpret_cast<u32*>(qhi + (size_t)tok*D_MODEL + col) = hp;
              *reinterpret_cast<u32*>(qlo + (size_t)tok*D_MODEL + col) = lp;
            } else {
              *reinterpret_cast<u32*>(khi + (size_t)tok*D_MODEL + col) = hp;
              *reinterpret_cast<u32*>(klo + (size_t)tok*D_MODEL + col) = lp;
              f32x2 fv; fv[0] = rot; fv[1] = rotp;
              *reinterpret_cast<f32x2*>(kout + (size_t)tok*D_MODEL + col) = fv;
            }
          }
        }
      }
    }
  }
}

// ================= WO GEMM: 128x128 double-buffered, x2 = resid + A @ woT =================
__global__ __launch_bounds__(256) void wo_gemm_kernel(
    const u16* __restrict__ A, const u16* __restrict__ Bt,
    const float* __restrict__ resid, float* __restrict__ Cout)
{
  const int K = D_MODEL, N = D_MODEL;
  __shared__ __align__(16) u16 As[2][128*32], Bs[2][128*32];   // 32 KB
  int tid = threadIdx.x, lane = tid & 63, wid = tid >> 6;
  int wm = wid >> 1, wn = wid & 1;
  int l15 = lane & 15, l4 = lane >> 4;
  size_t bm = (size_t)blockIdx.y * 128, bn = (size_t)blockIdx.x * 128;
  const u16* A0 = A + bm*K;  const u16* B0 = Bt + bn*K;
  f32x4 acc[4][4] = {};
  stage128x32(A0, K, 0, As[0], wid, lane);
  stage128x32(B0, K, 0, Bs[0], wid, lane);
  __syncthreads();
  int cur = 0;
  for (int kt = 0; kt < K; kt += 32) {
    if (kt + 32 < K) {
      int nxt = cur ^ 1;
      stage128x32(A0, K, kt + 32, As[nxt], wid, lane);
      stage128x32(B0, K, kt + 32, Bs[nxt], wid, lane);
    }
    bf16x8 a[4];
#pragma unroll
    for (int mi = 0; mi < 4; ++mi)
      a[mi] = fragLDS(As[cur], wm*64 + mi*16 + l15, l4, l15);
#pragma unroll
    for (int ni = 0; ni < 4; ++ni) {
      bf16x8 b = fragLDS(Bs[cur], wn*64 + ni*16 + l15, l4, l15);
#pragma unroll
      for (int mi = 0; mi < 4; ++mi)
        acc[mi][ni] = MFMA16(a[mi], b, acc[mi][ni]);
    }
    __syncthreads();
    cur ^= 1;
  }
#pragma unroll
  for (int mi = 0; mi < 4; ++mi)
#pragma unroll
    for (int ni = 0; ni < 4; ++ni)
#pragma unroll
      for (int r = 0; r < 4; ++r) {
        size_t row = bm + wm*64 + mi*16 + l4*4 + r;
        size_t col = bn + wn*64 + ni*16 + l15;
        Cout[row*N + col] = resid[row*N + col] + acc[mi][ni][r];
      }
}

// ================= wg2[d][e] = sum_i wo[d][i]*ffnw[i]*gw[i][e] =================
__global__ __launch_bounds__(64) void wg2_kernel(
    const float* __restrict__ wo, const float* __restrict__ ffnw,
    const float* __restrict__ gw, float* __restrict__ wg2)
{
  int d = blockIdx.x, lane = threadIdx.x;
  const float* wr = wo + (size_t)d * D_MODEL;
  float acc[8] = {0,0,0,0,0,0,0,0};
#pragma unroll
  for (int i = 0; i < 4; ++i) {
    int c = lane*4 + i*256;
    f32x4 wv = *reinterpret_cast<const f32x4*>(wr + c);
    f32x4 fv = *reinterpret_cast<const f32x4*>(ffnw + c);
#pragma unroll
    for (int j = 0; j < 4; ++j) {
      float a = wv[j] * fv[j];
      f32x4 g0 = *reinterpret_cast<const f32x4*>(gw + (size_t)(c + j)*NEXP);
      f32x4 g1 = *reinterpret_cast<const f32x4*>(gw + (size_t)(c + j)*NEXP + 4);
      acc[0]+=a*g0[0]; acc[1]+=a*g0[1]; acc[2]+=a*g0[2]; acc[3]+=a*g0[3];
      acc[4]+=a*g1[0]; acc[5]+=a*g1[1]; acc[6]+=a*g1[2]; acc[7]+=a*g1[3];
    }
  }
#pragma unroll
  for (int off = 32; off >= 1; off >>= 1)
#pragma unroll
    for (int e = 0; e < 8; ++e) acc[e] += __shfl_xor(acc[e], off);
  if (lane == 0) {
#pragma unroll
    for (int e = 0; e < 8; ++e) wg2[(size_t)d*NEXP + e] = acc[e];
  }
}

// ================= Vg[t][h][e] =================
__global__ __launch_bounds__(256) void vg_kernel(
    const float* __restrict__ vf, const float* __restrict__ wg2, float* __restrict__ Vg)
{
  int tok = blockIdx.x * 4 + (threadIdx.x >> 6);
  int lane = threadIdx.x & 63;
  int hh = lane >> 2, part = lane & 3;
  const float* vr = vf + (size_t)tok * D_MODEL + hh*64 + part*16;
  const float* gr = wg2 + (size_t)(hh*64 + part*16) * NEXP;
  float acc[8] = {0,0,0,0,0,0,0,0};
#pragma unroll
  for (int i = 0; i < 4; ++i) {
    f32x4 vv = *reinterpret_cast<const f32x4*>(vr + i*4);
#pragma unroll
    for (int j = 0; j < 4; ++j) {
      float a = vv[j];
      f32x4 g0 = *reinterpret_cast<const f32x4*>(gr + (size_t)(i*4 + j)*NEXP);
      f32x4 g1 = *reinterpret_cast<const f32x4*>(gr + (size_t)(i*4 + j)*NEXP + 4);
      acc[0]+=a*g0[0]; acc[1]+=a*g0[1]; acc[2]+=a*g0[2]; acc[3]+=a*g0[3];
      acc[4]+=a*g1[0]; acc[5]+=a*g1[1]; acc[6]+=a*g1[2]; acc[7]+=a*g1[3];
    }
  }
#pragma unroll
  for (int off = 1; off < 4; off <<= 1)
#pragma unroll
    for (int e = 0; e < 8; ++e) acc[e] += __shfl_xor(acc[e], off);
  if (part == 0) {
#pragma unroll
    for (int e = 0; e < 8; ++e) Vg[((size_t)tok*NHEAD + hh)*NEXP + e] = acc[e];
  }
}

// ================= flash attention v5: K and V both staged via global_load_lds =================
__global__ __launch_bounds__(256) void attn_kernel(
    const u16* __restrict__ Qhi, const u16* __restrict__ Qlo,
    const u16* __restrict__ Khi, const u16* __restrict__ Klo,
    const u16* __restrict__ vT, const float* __restrict__ Vg,
    u16* __restrict__ Ob, float* __restrict__ raw_ao)
{
  int id = blockIdx.x;
  int bh = id & 31, b = bh >> 4, h = bh & 15;
  int rr_ = id >> 8, kk_ = (id >> 5) & 7;
  int qt = (rr_ == 0) ? (31 - kk_) : (rr_ == 1) ? (16 + kk_)
         : (rr_ == 2) ? (15 - kk_) : kk_;
  int tid = threadIdx.x, lane = tid & 63, wid = tid >> 6;
  int l15 = lane & 15, l4 = lane >> 4;

  __shared__ __align__(16) u16 VTs[64*64];
  __shared__ __align__(16) u16 Pl[4][16][72];
  __shared__ float VgS[64][12];
  __shared__ __align__(16) u16 KhS[64*64], KlS[64*64];

  const u16* vTb = vT + ((size_t)bh * 64) * T_SEQ;   // rows d, cols tok

  size_t qoff = ((size_t)(b*T_SEQ + qt*64 + wid*16)) * D_MODEL + h*64;
  bf16x8 qhiF[2], qloF[2];
#pragma unroll
  for (int s = 0; s < 2; ++s) {
    qhiF[s] = frag_b128(Qhi + qoff + (size_t)l15*D_MODEL + s*32 + l4*8);
    qloF[s] = frag_b128(Qlo + qoff + (size_t)l15*D_MODEL + s*32 + l4*8);
  }
  float m_r[4], l_r[4];
  f32x4 racc4[4][2] = {};
  f32x4 oacc[4] = {};
#pragma unroll
  for (int r = 0; r < 4; ++r) { m_r[r] = -1e30f; l_r[r] = 0.f; }

  for (int kt = 0; kt <= qt; ++kt) {
    __syncthreads();
    {
      const u16* kbH = Khi + ((size_t)(b*T_SEQ + kt*64))*D_MODEL + h*64;
      const u16* kbL = Klo + ((size_t)(b*T_SEQ + kt*64))*D_MODEL + h*64;
      stage64x64(kbH, D_MODEL, 0, KhS, wid, lane);
      stage64x64(kbL, D_MODEL, 0, KlS, wid, lane);
      stage64x64(vTb, T_SEQ, kt*64, VTs, wid, lane);   // [64 d][64 keys]
    }
    if (tid < 128) {
      int key = tid >> 1, eh = (tid & 1) * 4;
      const float* gsrc = Vg + ((size_t)(b*T_SEQ + kt*64 + key)*NHEAD + h)*NEXP + eh;
      *reinterpret_cast<f32x4*>(&VgS[key][eh]) = *reinterpret_cast<const f32x4*>(gsrc);
    }
    __syncthreads();

    f32x4 sacc[4] = {};
    __builtin_amdgcn_s_setprio(1);
#pragma unroll
    for (int n = 0; n < 4; ++n) {
#pragma unroll
      for (int s = 0; s < 2; ++s) {
        bf16x8 khiF = fragLDS64(KhS, n*16 + l15, s, l4, l15);
        bf16x8 kloF = fragLDS64(KlS, n*16 + l15, s, l4, l15);
        sacc[n] = MFMA16(qhiF[s], khiF, sacc[n]);
        sacc[n] = MFMA16(qhiF[s], kloF, sacc[n]);
        sacc[n] = MFMA16(qloF[s], khiF, sacc[n]);
      }
    }
    __builtin_amdgcn_s_setprio(0);
#pragma unroll
    for (int n = 0; n < 4; ++n)
#pragma unroll
      for (int r = 0; r < 4; ++r)
        sacc[n][r] *= 0.125f;
    if (kt == qt) {
      int q0 = qt*64 + wid*16 + l4*4;
      int k00 = kt*64 + l15;
#pragma unroll
      for (int n = 0; n < 4; ++n)
#pragma unroll
        for (int r = 0; r < 4; ++r)
          if (k00 + n*16 > q0 + r) sacc[n][r] = -1e30f;
    }
    float rm[4];
#pragma unroll
    for (int r = 0; r < 4; ++r) {
      float v = fmaxf(fmaxf(sacc[0][r], sacc[1][r]), fmaxf(sacc[2][r], sacc[3][r]));
#pragma unroll
      for (int off = 1; off < 16; off <<= 1) v = fmaxf(v, __shfl_xor(v, off));
      rm[r] = v;
    }
    int needp = (rm[0] > m_r[0]+8.f) | (rm[1] > m_r[1]+8.f) |
                (rm[2] > m_r[2]+8.f) | (rm[3] > m_r[3]+8.f);
    if (__any(needp)) {
#pragma unroll
      for (int r = 0; r < 4; ++r) {
        float mn = fmaxf(m_r[r], rm[r]);
        float corr = __expf(m_r[r] - mn);
        m_r[r] = mn;
        l_r[r] *= corr;
        racc4[r][0] *= corr; racc4[r][1] *= corr;
#pragma unroll
        for (int n = 0; n < 4; ++n) oacc[n][r] *= corr;
      }
    }
#pragma unroll
    for (int r = 0; r < 4; ++r) {
      float rs = 0.f;
#pragma unroll
      for (int n = 0; n < 4; ++n) {
        float pp = __expf(sacc[n][r] - m_r[r]);
        sacc[n][r] = pp;
        rs += pp;
      }
#pragma unroll
      for (int off = 1; off < 16; off <<= 1) rs += __shfl_xor(rs, off);
      l_r[r] += rs;
    }
#pragma unroll
    for (int n = 0; n < 4; ++n)
#pragma unroll
      for (int r = 0; r < 4; ++r)
        Pl[wid][l4*4 + r][n*16 + l15] = cvt_bf16(sacc[n][r]);
#pragma unroll
    for (int n = 0; n < 4; ++n) {
      f32x4 g0 = *reinterpret_cast<const f32x4*>(&VgS[n*16 + l15][0]);
      f32x4 g1 = *reinterpret_cast<const f32x4*>(&VgS[n*16 + l15][4]);
#pragma unroll
      for (int r = 0; r < 4; ++r) {
        float pp = sacc[n][r];
        racc4[r][0] += g0 * pp;
        racc4[r][1] += g1 * pp;
      }
    }
    __builtin_amdgcn_s_setprio(1);
#pragma unroll
    for (int s = 0; s < 2; ++s) {
      bf16x8 pa = frag_b128(&Pl[wid][l15][s*32 + l4*8]);
#pragma unroll
      for (int n = 0; n < 4; ++n) {
        bf16x8 vb8 = fragLDS64(VTs, n*16 + l15, s, l4, l15);
        oacc[n] = MFMA16(pa, vb8, oacc[n]);
      }
    }
    __builtin_amdgcn_s_setprio(0);
  }
  float inv[4];
#pragma unroll
  for (int r = 0; r < 4; ++r) inv[r] = 1.0f / l_r[r];
  size_t obase = ((size_t)(b*T_SEQ + qt*64 + wid*16))*D_MODEL + h*64;
#pragma unroll
  for (int n = 0; n < 4; ++n)
#pragma unroll
    for (int r = 0; r < 4; ++r)
      Ob[obase + (size_t)(l4*4 + r)*D_MODEL + n*16 + l15] = cvt_bf16(oacc[n][r]*inv[r]);
  float rv[4][8];
#pragma unroll
  for (int r = 0; r < 4; ++r)
#pragma unroll
    for (int e = 0; e < 8; ++e)
      rv[r][e] = (e < 4) ? racc4[r][0][e] : racc4[r][1][e-4];
#pragma unroll
  for (int off = 1; off < 16; off <<= 1)
#pragma unroll
    for (int r = 0; r < 4; ++r)
#pragma unroll
      for (int e = 0; e < 8; ++e)
        rv[r][e] += __shfl_xor(rv[r][e], off);
  if (l15 == 0) {
#pragma unroll
    for (int r = 0; r < 4; ++r) {
      size_t tokg = (size_t)(b*T_SEQ) + qt*64 + wid*16 + l4*4 + r;
#pragma unroll
      for (int e = 0; e < 8; ++e)
        raw_ao[(tokg*NHEAD + h)*NEXP + e] = rv[r][e]*inv[r];
    }
  }
}

// ================= gate: fp32 logits, top-2 =================
__global__ void zero_counts_kernel(int* counts) {
  if (threadIdx.x < NEXP) counts[threadIdx.x] = 0;
}

__global__ __launch_bounds__(256) void gate2_kernel(
    const float* __restrict__ x, const float* __restrict__ x2,
    const float* __restrict__ ffnw, const float* __restrict__ gw,
    const float* __restrict__ raw_ao,
    int* __restrict__ gidx, float* __restrict__ gwt, int* __restrict__ counts)
{
  int tok = blockIdx.x * 4 + (threadIdx.x >> 6);
  int lane = threadIdx.x & 63;
  const float* xr = x + (size_t)tok * D_MODEL;
  const float* x2r = x2 + (size_t)tok * D_MODEL;
  float ss = 0.f;
  float lg[8] = {0,0,0,0,0,0,0,0};
#pragma unroll
  for (int i = 0; i < 4; ++i) {
    int d = lane*4 + i*256;
    f32x4 xv = *reinterpret_cast<const f32x4*>(xr + d);
    f32x4 x2v = *reinterpret_cast<const f32x4*>(x2r + d);
    f32x4 wv = *reinterpret_cast<const f32x4*>(ffnw + d);
    ss += x2v[0]*x2v[0] + x2v[1]*x2v[1] + x2v[2]*x2v[2] + x2v[3]*x2v[3];
#pragma unroll
    for (int j = 0; j < 4; ++j) {
      float a = xv[j]*wv[j];
      f32x4 g0 = *reinterpret_cast<const f32x4*>(gw + (size_t)(d + j)*NEXP);
      f32x4 g1 = *reinterpret_cast<const f32x4*>(gw + (size_t)(d + j)*NEXP + 4);
      lg[0]+=a*g0[0]; lg[1]+=a*g0[1]; lg[2]+=a*g0[2]; lg[3]+=a*g0[3];
      lg[4]+=a*g1[0]; lg[5]+=a*g1[1]; lg[6]+=a*g1[2]; lg[7]+=a*g1[3];
    }
  }
#pragma unroll
  for (int off = 1; off < 64; off <<= 1) {
    ss += __shfl_xor(ss, off);
#pragma unroll
    for (int e = 0; e < 8; ++e) lg[e] += __shfl_xor(lg[e], off);
  }
  float ah[8] = {0,0,0,0,0,0,0,0};
  if (lane < 16) {
    const float* ar = raw_ao + ((size_t)tok*NHEAD + lane)*NEXP;
#pragma unroll
    for (int e = 0; e < 8; ++e) ah[e] = ar[e];
  }
#pragma unroll
  for (int off = 1; off < 16; off <<= 1)
#pragma unroll
    for (int e = 0; e < 8; ++e) ah[e] += __shfl_xor(ah[e], off);
  if (lane == 0) {
    float rms = rsqrtf(ss*(1.0f/D_MODEL) + 1e-6f);
    float lo_[8], pp[8];
    float mx = -1e30f;
#pragma unroll
    for (int e = 0; e < 8; ++e) { lo_[e] = (lg[e] + ah[e]) * rms; mx = fmaxf(mx, lo_[e]); }
    float sum = 0.f;
#pragma unroll
    for (int e = 0; e < 8; ++e) { pp[e] = __expf(lo_[e] - mx); sum += pp[e]; }
    float isum = 1.0f/sum;
#pragma unroll
    for (int e = 0; e < 8; ++e) pp[e] *= isum;
    int i0 = 0;
    for (int e = 1; e < 8; ++e) if (pp[e] > pp[i0]) i0 = e;
    int i1 = (i0 == 0) ? 1 : 0;
    for (int e = 0; e < 8; ++e) if (e != i0 && pp[e] > pp[i1]) i1 = e;
    float v0 = pp[i0], v1 = pp[i1];
    float wnorm = 1.0f/(v0 + v1 + 1e-8f);
    gidx[2*tok] = i0; gidx[2*tok+1] = i1;
    gwt[2*tok] = v0*wnorm; gwt[2*tok+1] = v1*wnorm;
    atomicAdd(&counts[i0], 1); atomicAdd(&counts[i1], 1);
  }
}

// ================= routing =================
__global__ __launch_bounds__(256) void scan_kernel(
    const int* __restrict__ counts, int* __restrict__ base, int* __restrict__ fill,
    int* __restrict__ blk_expert, int* __restrict__ perm_token)
{
  if (threadIdx.x == 0) {
    int b = 0, blk = 0;
    for (int e = 0; e < NEXP; ++e) {
      base[e] = b;
      fill[e] = 0;
      int nb = (counts[e] + 127) >> 7;
      for (int i = 0; i < nb; ++i) blk_expert[blk++] = e;
      b += nb << 7;
    }
    for (; blk < MAXBLK; ++blk) blk_expert[blk] = -1;
  }
  for (int i = threadIdx.x; i < SLOTS; i += 256) perm_token[i] = -1;
}

__global__ __launch_bounds__(256) void scatter_kernel(
    const int* __restrict__ gidx, const int* __restrict__ base, int* __restrict__ fill,
    int* __restrict__ perm_token, int* __restrict__ tok_slot)
{
  int t = blockIdx.x * 256 + threadIdx.x;
  if (t >= NTOK) return;
#pragma unroll
  for (int r = 0; r < 2; ++r) {
    int e = gidx[2*t + r];
    int pos = base[e] + atomicAdd(&fill[e], 1);
    perm_token[pos] = t;
    tok_slot[2*t + r] = pos;
  }
}

// ================= MoE GEMM1: BN=64, BK=64 =================
__global__ __launch_bounds__(256) void moe_gemm1_kernel(
    const u16* __restrict__ Ah, const u16* __restrict__ W1t, const u16* __restrict__ W3t,
    const int* __restrict__ perm_token, const int* __restrict__ blk_expert,
    u16* __restrict__ tbuf)
{
  int mb = blockIdx.y;
  int e = blk_expert[mb];
  if (e < 0) return;
  const int K = D_MODEL;
  __shared__ __align__(16) u16 As[128*64], B1s[64*64], B3s[64*64];  // 32 KB
  int tid = threadIdx.x, lane = tid & 63, wid = tid >> 6;
  int wm = wid >> 1, wn = wid & 1;
  int l15 = lane & 15, l4 = lane >> 4;
  size_t bn = (size_t)blockIdx.x * 64;
  const u16* w1e = W1t + (size_t)e * HID_DIM * D_MODEL + bn*K;
  const u16* w3e = W3t + (size_t)e * HID_DIM * D_MODEL + bn*K;
  int rl = lane >> 3, cc = lane & 7;
  int tokA[4];
#pragma unroll
  for (int g = 0; g < 4; ++g) {
    int row = wid*32 + g*8 + rl;
    int t = perm_token[mb*128 + row];
    tokA[g] = t < 0 ? 0 : t;
  }
  f32x4 acc1[4][2] = {}, acc3[4][2] = {};
  for (int kt = 0; kt < K; kt += 64) {
    __syncthreads();
#pragma unroll
    for (int g = 0; g < 4; ++g) {
      int row = wid*32 + g*8 + rl;
      int chunk = cc ^ (row & 7);
      gload16(Ah + (size_t)tokA[g]*K + kt + chunk*8, As + (size_t)(wid*32 + g*8)*64);
    }
    stage64x64(w1e, K, kt, B1s, wid, lane);
    stage64x64(w3e, K, kt, B3s, wid, lane);
    __syncthreads();
#pragma unroll
    for (int s = 0; s < 2; ++s) {
      bf16x8 a[4];
#pragma unroll
      for (int mi = 0; mi < 4; ++mi)
        a[mi] = fragLDS64(As, wm*64 + mi*16 + l15, s, l4, l15);
#pragma unroll
      for (int ni = 0; ni < 2; ++ni) {
        int row = wn*32 + ni*16 + l15;
        bf16x8 b1 = fragLDS64(B1s, row, s, l4, l15);
        bf16x8 b3 = fragLDS64(B3s, row, s, l4, l15);
#pragma unroll
        for (int mi = 0; mi < 4; ++mi) {
          acc1[mi][ni] = MFMA16(a[mi], b1, acc1[mi][ni]);
          acc3[mi][ni] = MFMA16(a[mi], b3, acc3[mi][ni]);
        }
      }
    }
  }
  int evenl = !(lane & 1);
#pragma unroll
  for (int mi = 0; mi < 4; ++mi)
#pragma unroll
    for (int ni = 0; ni < 2; ++ni)
#pragma unroll
      for (int r = 0; r < 4; ++r) {
        size_t slot = (size_t)mb*128 + wm*64 + mi*16 + l4*4 + r;
        size_t col = bn + wn*32 + ni*16 + l15;
        float h1 = acc1[mi][ni][r], h3 = acc3[mi][ni][r];
        float t = h1 * __builtin_amdgcn_rcpf(1.0f + __expf(-h1)) * h3;
        float tp = __shfl_xor(t, 1);
        if (evenl) {
          u32 pk = (u32)cvt_bf16(t) | ((u32)cvt_bf16(tp) << 16);
          *reinterpret_cast<u32*>(tbuf + slot*HID_DIM + col) = pk;
        }
      }
}

// ================= MoE GEMM2: BK=32 double-buffered: y = t @ w2T =================
__global__ __launch_bounds__(256) void moe_gemm2_kernel(
    const u16* __restrict__ tbuf, const u16* __restrict__ W2t,
    const int* __restrict__ blk_expert, u16* __restrict__ ybuf)
{
  int mb = blockIdx.y;
  int e = blk_expert[mb];
  if (e < 0) return;
  const int K = HID_DIM, N = D_MODEL;
  __shared__ __align__(16) u16 As[2][128*32], Bs[2][128*32];   // 32 KB
  int tid = threadIdx.x, lane = tid & 63, wid = tid >> 6;
  int wm = wid >> 1, wn = wid & 1;
  int l15 = lane & 15, l4 = lane >> 4;
  size_t bm = (size_t)mb * 128, bn = (size_t)blockIdx.x * 128;
  const u16* A0 = tbuf + bm*K;
  const u16* B0 = W2t + (size_t)e * D_MODEL * HID_DIM + bn*K;
  f32x4 acc[4][4] = {};
  stage128x32(A0, K, 0, As[0], wid, lane);
  stage128x32(B0, K, 0, Bs[0], wid, lane);
  __syncthreads();
  int cur = 0;
  for (int kt = 0; kt < K; kt += 32) {
    if (kt + 32 < K) {
      int nxt = cur ^ 1;
      stage128x32(A0, K, kt + 32, As[nxt], wid, lane);
      stage128x32(B0, K, kt + 32, Bs[nxt], wid, lane);
    }
    bf16x8 a[4];
#pragma unroll
    for (int mi = 0; mi < 4; ++mi)
      a[mi] = fragLDS(As[cur], wm*64 + mi*16 + l15, l4, l15);
#pragma unroll
    for (int ni = 0; ni < 4; ++ni) {
      bf16x8 b = fragLDS(Bs[cur], wn*64 + ni*16 + l15, l4, l15);
#pragma unroll
      for (int mi = 0; mi < 4; ++mi)
        acc[mi][ni] = MFMA16(a[mi], b, acc[mi][ni]);
    }
    __syncthreads();
    cur ^= 1;
  }
  int evenl = !(lane & 1);
#pragma unroll
  for (int mi = 0; mi < 4; ++mi)
#pragma unroll
    for (int ni = 0; ni < 4; ++ni)
#pragma unroll
      for (int r = 0; r < 4; ++r) {
        float v = acc[mi][ni][r];
        float vp = __shfl_xor(v, 1);
        if (evenl) {
          size_t slot = bm + wm*64 + mi*16 + l4*4 + r;
          size_t col = bn + wn*64 + ni*16 + l15;
          u32 pk = (u32)cvt_bf16(v) | ((u32)cvt_bf16(vp) << 16);
          *reinterpret_cast<u32*>(ybuf + slot*N + col) = pk;
        }
      }
}

// ================= combine =================
__global__ __launch_bounds__(256) void combine_kernel(
    const float* __restrict__ x2, const u16* __restrict__ ybuf,
    const int* __restrict__ tok_slot, const float* __restrict__ gwt,
    float* __restrict__ xout)
{
  int t = blockIdx.x;
  int c = threadIdx.x * 4;
  int s0 = tok_slot[2*t], s1 = tok_slot[2*t+1];
  float w0 = gwt[2*t], w1 = gwt[2*t+1];
  f32x4 xv = *reinterpret_cast<const f32x4*>(x2 + (size_t)t * D_MODEL + c);
  const u16* y0 = ybuf + (size_t)s0 * D_MODEL + c;
  const u16* y1 = ybuf + (size_t)s1 * D_MODEL + c;
  f32x4 o;
#pragma unroll
  for (int j = 0; j < 4; ++j)
    o[j] = xv[j] + w0 * bf2f(y0[j]) + w1 * bf2f(y1[j]);
  *reinterpret_cast<f32x4*>(xout + (size_t)t * D_MODEL + c) = o;
}

// ================= host launch =================
extern "C" void kernel_launch(void* const* d_in, const int* in_sizes, int n_in,
                              void* d_out, int out_size, void* d_ws, size_t ws_size,
                              hipStream_t stream)
{
  (void)in_sizes; (void)n_in; (void)out_size; (void)ws_size;
  const float* x     = (const float*)d_in[0];
  const float* freqs = (const float*)d_in[1];
  const float* attnw = (const float*)d_in[3];
  const float* ffnw  = (const float*)d_in[4];
  const float* wq    = (const float*)d_in[5];
  const float* wk    = (const float*)d_in[6];
  const float* wv    = (const float*)d_in[7];
  const float* wo    = (const float*)d_in[8];
  const float* gw    = (const float*)d_in[9];
  const float* w1    = (const float*)d_in[10];
  const float* w2    = (const float*)d_in[11];
  const float* w3    = (const float*)d_in[12];
  float* xout = (float*)d_out;
  float* kout = xout + (size_t)NTOK * D_MODEL;
  float* vout = kout + (size_t)NTOK * D_MODEL;

  const size_t PLANE = (size_t)NTOK * D_MODEL * 2;      // 8,388,608
  const size_t QKVT  = (size_t)3 * D_MODEL * D_MODEL * 2; // 6,291,456
  const size_t TBUFB = (size_t)SLOTS * HID_DIM * 2;     // 37,748,736
  const size_t WEXP  = (size_t)NEXP * D_MODEL * HID_DIM * 2; // 33,554,432
  char* base = (char*)d_ws;
  // region P: [0, 37.75M) : hhi|hlo|wqkvT planes / woT ; later tbuf
  u16* hhi      = (u16*)(base);
  u16* hlo      = (u16*)(base + PLANE);
  u16* wqkvT_hi = (u16*)(base + 2*PLANE);
  u16* wqkvT_lo = (u16*)(base + 2*PLANE + QKVT);
  u16* woT      = (u16*)(base + 2*PLANE);               // after qkv gemm
  u16* tbuf     = (u16*)(base);                          // moe1..moe2
  // region Q: q/k planes + vbf ; later w1T ; later ybuf
  char* Qb = base + TBUFB;
  u16* qhi = (u16*)(Qb);
  u16* qlo = (u16*)(Qb + PLANE);
  u16* khi = (u16*)(Qb + 2*PLANE);
  u16* klo = (u16*)(Qb + 3*PLANE);
  u16* vbf = (u16*)(Qb + 4*PLANE);
  u16* w1T  = (u16*)(Qb);                                // after attn
  u16* ybuf = (u16*)(Qb);                                // after moe1
  // region S: aobf | vT ; later w3T ; later w2T
  char* Sb = Qb + 5*PLANE;
  u16* aobf = (u16*)(Sb);
  u16* vT   = (u16*)(Sb + PLANE);                        // [32 bh][64 d][2048 tok]
  u16* w3T  = (u16*)(Sb);                                // after wo gemm (aobf+vT dead)
  u16* w2T  = (u16*)(Sb);                                // after moe1
  // region T: hf ; region X: x2
  char* Tb = Sb + WEXP;
  u16* hf = (u16*)(Tb);
  float* x2 = (float*)(Tb + PLANE);
  // smalls
  char* p = Tb + PLANE + (size_t)NTOK * D_MODEL * 4;
  float* wg2    = (float*)p;  p += 32768;
  float* Vg     = (float*)p;  p += (size_t)NTOK*NHEAD*NEXP*4;
  float* raw_ao = (float*)p;  p += (size_t)NTOK*NHEAD*NEXP*4;
  int*   gidx   = (int*)p;    p += 32768;
  float* gwt    = (float*)p;  p += 32768;
  int*   tok_slot = (int*)p;  p += 32768;
  int*   perm   = (int*)p;    p += SLOTS*4;
  int*   counts = (int*)p;
  int*   base_  = counts + 8;
  int*   fill_  = counts + 16;
  int*   blk_e  = counts + 24;

  dim3 blk(256);
  // 1. norms + small precomputes
  rmsnorm_kernel<1><<<NTOK, blk, 0, stream>>>(x, attnw, hhi, hlo);
  wg2_kernel<<<D_MODEL, 64, 0, stream>>>(wo, ffnw, gw, wg2);
  zero_counts_kernel<<<1, 64, 0, stream>>>(counts);
  // 2. fused transpose+split wq/wk/wv (one launch, z=3)
  dim3 tg3(16, 16, 3);
  transpose_qkv_kernel<<<tg3, blk, 0, stream>>>(wq, wk, wv, wqkvT_hi, wqkvT_lo);
  // 3. fused QKV split-GEMM + rope epilogue (round-11 dbuf, BN=128)
  dim3 gqkv(24, 32);
  qkv_gemm_kernel<<<gqkv, blk, 0, stream>>>(hhi, hlo, wqkvT_hi, wqkvT_lo, freqs,
                                            qhi, qlo, khi, klo, vbf, kout, vout);
  // 4. V transpose, woT, Vg
  dim3 gvt(T_SEQ/64, 32);
  v_transpose_kernel<<<gvt, blk, 0, stream>>>(vbf, vT);
  dim3 tg(16, 16);
  transpose_kernel<0><<<tg, blk, 0, stream>>>(wo, woT, nullptr, D_MODEL, D_MODEL);
  vg_kernel<<<NTOK/4, blk, 0, stream>>>(vout, wg2, Vg);
  // 5. attention: 1024 blocks, zig-zag balanced qt, K+V staged in LDS
  attn_kernel<<<dim3(1024), blk, 0, stream>>>(qhi, qlo, khi, klo, vT, Vg, aobf, raw_ao);
  // 6. w1T, WO gemm (double-buffered)
  dim3 tw13(HID_DIM/64, D_MODEL/64, NEXP);
  transpose_kernel<0><<<tw13, blk, 0, stream>>>(w1, w1T, nullptr, D_MODEL, HID_DIM);
  dim3 g88(D_MODEL/128, NTOK/128);
  wo_gemm_kernel<<<g88, blk, 0, stream>>>(aobf, woT, x, x2);
  // 7. w3T, norm, gate, routing
  transpose_kernel<0><<<tw13, blk, 0, stream>>>(w3, w3T, nullptr, D_MODEL, HID_DIM);
  rmsnorm_kernel<0><<<NTOK, blk, 0, stream>>>(x2, ffnw, hf, nullptr);
  gate2_kernel<<<NTOK/4, blk, 0, stream>>>(x, x2, ffnw, gw, raw_ao, gidx, gwt, counts);
  scan_kernel<<<1, blk, 0, stream>>>(counts, base_, fill_, blk_e, perm);
  scatter_kernel<<<NTOK/256, blk, 0, stream>>>(gidx, base_, fill_, perm, tok_slot);
  // 8. MoE gemm1: BN=64 grid
  dim3 g1(HID_DIM/64, MAXBLK);
  moe_gemm1_kernel<<<g1, blk, 0, stream>>>(hf, w1T, w3T, perm, blk_e, tbuf);
  // 9. w2T, gemm2 (double-buffered)
  dim3 tw2(D_MODEL/64, HID_DIM/64, NEXP);
  transpose_kernel<0><<<tw2, blk, 0, stream>>>(w2, w2T, nullptr, HID_DIM, D_MODEL);
  dim3 g2(D_MODEL/128, MAXBLK);
  moe_gemm2_kernel<<<g2, blk, 0, stream>>>(tbuf, w2T, blk_e, ybuf);
  // 10. combine
  combine_kernel<<<NTOK, blk, 0, stream>>>(x2, ybuf, tok_slot, gwt, xout);
}

// Round 15
// 726.054 us; speedup vs baseline: 1.1973x; 1.1006x over previous
//
#include <hip/hip_runtime.h>

#define T_SEQ   2048
#define D_MODEL 1024
#define NHEAD   16
#define NEXP    8
#define HID_DIM 2048
#define NTOK    4096
#define MAXBLK  72
#define SLOTS   9216

typedef unsigned short u16;
typedef unsigned int   u32;
typedef __bf16 bf16_t;
typedef bf16_t bf16x8 __attribute__((ext_vector_type(8)));
typedef float  f32x4  __attribute__((ext_vector_type(4)));
typedef float  f32x2  __attribute__((ext_vector_type(2)));
typedef u32    u32x4  __attribute__((ext_vector_type(4)));

typedef __attribute__((address_space(1))) const void* gptr1_t;
typedef __attribute__((address_space(3))) void*       lptr3_t;

__device__ __forceinline__ u16 f2bf_bits(float f) {
  u32 u = __builtin_bit_cast(u32, f);
  u += 0x7FFFu + ((u >> 16) & 1u);
  return (u16)(u >> 16);
}
__device__ __forceinline__ float bf2f(u16 s) {
  return __builtin_bit_cast(float, (u32)s << 16);
}
__device__ __forceinline__ bf16x8 frag_b128(const u16* p) {
  return *reinterpret_cast<const bf16x8*>(p);
}
__device__ __forceinline__ u16 cvt_bf16(float f) {
  return __builtin_bit_cast(u16, (__bf16)f);
}
#define MFMA16(a,b,c) __builtin_amdgcn_mfma_f32_16x16x32_bf16((a),(b),(c),0,0,0)

// ---- async global->LDS, 16B per lane, wave-uniform LDS base ----
__device__ __forceinline__ void gload16(const void* g, void* l) {
  __builtin_amdgcn_global_load_lds((gptr1_t)g, (lptr3_t)l, 16, 0, 0);
}

// ---- BK=32 tile staging: [128][32]-u16, source-side XOR swizzle ----
__device__ __forceinline__ void stage128x32(const u16* gbase, size_t ldk, int kt,
                                            u16* lds, int wid, int lane) {
  int rl = lane >> 2, cc = lane & 3;
#pragma unroll
  for (int h = 0; h < 2; ++h) {
    int row = wid*32 + h*16 + rl;
    int chunk = cc ^ ((row >> 1) & 3);
    gload16(gbase + (size_t)row*ldk + kt + chunk*8, lds + (size_t)(wid*32 + h*16)*32);
  }
}
__device__ __forceinline__ bf16x8 fragLDS(const u16* lds, int row, int l4, int l15) {
  int chunk = l4 ^ ((l15 >> 1) & 3);
  return frag_b128(lds + row*32 + chunk*8);
}

// ---- BK=64, 64-row tile staging: [64][64]-u16 ----
__device__ __forceinline__ void stage64x64(const u16* gbase, size_t ldk, int kt,
                                           u16* lds, int wid, int lane) {
  int rl = lane >> 3, cc = lane & 7;
#pragma unroll
  for (int g = 0; g < 2; ++g) {
    int row = wid*16 + g*8 + rl;
    int chunk = cc ^ (row & 7);
    gload16(gbase + (size_t)row*ldk + kt + chunk*8, lds + (size_t)(wid*16 + g*8)*64);
  }
}
__device__ __forceinline__ bf16x8 fragLDS64(const u16* lds, int row, int s, int l4, int l15) {
  int chunk = (s*4 + l4) ^ (l15 & 7);   // row&7 == l15&7 (row = 16m + l15)
  return frag_b128(lds + row*64 + chunk*8);
}

// ================= rmsnorm (optionally split hi/lo bf16) =================
template<int SPLIT>
__global__ __launch_bounds__(256) void rmsnorm_kernel(
    const float* __restrict__ x, const float* __restrict__ w,
    u16* __restrict__ hi, u16* __restrict__ lo)
{
  int row = blockIdx.x, tid = threadIdx.x;
  const float* xr = x + (size_t)row * D_MODEL;
  f32x4 v = *reinterpret_cast<const f32x4*>(xr + tid * 4);
  float ss = v[0]*v[0] + v[1]*v[1] + v[2]*v[2] + v[3]*v[3];
#pragma unroll
  for (int off = 32; off >= 1; off >>= 1) ss += __shfl_xor(ss, off);
  __shared__ float part[4];
  if ((tid & 63) == 0) part[tid >> 6] = ss;
  __syncthreads();
  float rms = rsqrtf((part[0]+part[1]+part[2]+part[3]) * (1.0f/D_MODEL) + 1e-6f);
  f32x4 wv = *reinterpret_cast<const f32x4*>(w + tid * 4);
  u32 hw0=0, hw1=0, lw0=0, lw1=0;
#pragma unroll
  for (int j = 0; j < 4; ++j) {
    float f = v[j] * rms * wv[j];
    u16 hb = f2bf_bits(f);
    if (j < 2) hw0 |= (u32)hb << (16*j); else hw1 |= (u32)hb << (16*(j-2));
    if (SPLIT) {
      u16 lb = f2bf_bits(f - bf2f(hb));
      if (j < 2) lw0 |= (u32)lb << (16*j); else lw1 |= (u32)lb << (16*(j-2));
    }
  }
  u32* hp = reinterpret_cast<u32*>(hi + (size_t)row * D_MODEL + tid * 4);
  hp[0] = hw0; hp[1] = hw1;
  if (SPLIT) {
    u32* lp = reinterpret_cast<u32*>(lo + (size_t)row * D_MODEL + tid * 4);
    lp[0] = lw0; lp[1] = lw1;
  }
}

// ================= weight prep: transpose f32 [R][C] -> bf16 [C][R] =================
template<int SPLIT>
__global__ __launch_bounds__(256) void transpose_kernel(
    const float* __restrict__ src, u16* __restrict__ dhi, u16* __restrict__ dlo,
    int R, int C)
{
  __shared__ float tile[64][65];
  src += (size_t)blockIdx.z * R * C;
  dhi += (size_t)blockIdx.z * R * C;
  if (SPLIT) dlo += (size_t)blockIdx.z * R * C;
  int r0 = blockIdx.y*64, c0 = blockIdx.x*64;
  int t = threadIdx.x;
  int lr = t>>2, lc4 = (t&3)*16;
#pragma unroll
  for (int i = 0; i < 4; ++i)
    *reinterpret_cast<f32x4*>(&tile[lr][lc4 + i*4]) =
        *reinterpret_cast<const f32x4*>(src + (size_t)(r0+lr)*C + c0 + lc4 + i*4);
  __syncthreads();
#pragma unroll
  for (int h = 0; h < 2; ++h) {
    int oc = h*32 + (t>>3);
    int ok = (t&7)*8;
    union { u16 a[8]; u32x4 v; } hb, lb;
#pragma unroll
    for (int j = 0; j < 8; ++j) {
      float f = tile[ok+j][oc];
      hb.a[j] = f2bf_bits(f);
      if (SPLIT) lb.a[j] = f2bf_bits(f - bf2f(hb.a[j]));
    }
    *reinterpret_cast<u32x4*>(dhi + (size_t)(c0+oc)*R + r0 + ok) = hb.v;
    if (SPLIT)
      *reinterpret_cast<u32x4*>(dlo + (size_t)(c0+oc)*R + r0 + ok) = lb.v;
  }
}

// fused wq/wk/wv transpose (split): z selects source
__global__ __launch_bounds__(256) void transpose_qkv_kernel(
    const float* __restrict__ wq, const float* __restrict__ wk, const float* __restrict__ wv,
    u16* __restrict__ dhi, u16* __restrict__ dlo)
{
  __shared__ float tile[64][65];
  int z = blockIdx.z;
  const float* src = (z == 0) ? wq : ((z == 1) ? wk : wv);
  dhi += (size_t)z * D_MODEL * D_MODEL;
  dlo += (size_t)z * D_MODEL * D_MODEL;
  int r0 = blockIdx.y*64, c0 = blockIdx.x*64;
  int t = threadIdx.x;
  int lr = t>>2, lc4 = (t&3)*16;
#pragma unroll
  for (int i = 0; i < 4; ++i)
    *reinterpret_cast<f32x4*>(&tile[lr][lc4 + i*4]) =
        *reinterpret_cast<const f32x4*>(src + (size_t)(r0+lr)*D_MODEL + c0 + lc4 + i*4);
  __syncthreads();
#pragma unroll
  for (int h = 0; h < 2; ++h) {
    int oc = h*32 + (t>>3);
    int ok = (t&7)*8;
    union { u16 a[8]; u32x4 v; } hb, lb;
#pragma unroll
    for (int j = 0; j < 8; ++j) {
      float f = tile[ok+j][oc];
      hb.a[j] = f2bf_bits(f);
      lb.a[j] = f2bf_bits(f - bf2f(hb.a[j]));
    }
    *reinterpret_cast<u32x4*>(dhi + (size_t)(c0+oc)*D_MODEL + r0 + ok) = hb.v;
    *reinterpret_cast<u32x4*>(dlo + (size_t)(c0+oc)*D_MODEL + r0 + ok) = lb.v;
  }
}

// fused w1/w3 transpose: z in [0,16): e = z&7, sel = z>>3
__global__ __launch_bounds__(256) void transpose_w13_kernel(
    const float* __restrict__ w1, const float* __restrict__ w3,
    u16* __restrict__ w1T, u16* __restrict__ w3T)
{
  __shared__ float tile[64][65];
  int z = blockIdx.z;
  int e = z & 7, sel = z >> 3;
  const float* src = (sel ? w3 : w1) + (size_t)e * D_MODEL * HID_DIM;
  u16* dst = (sel ? w3T : w1T) + (size_t)e * D_MODEL * HID_DIM;
  const int R = D_MODEL, C = HID_DIM;
  int r0 = blockIdx.y*64, c0 = blockIdx.x*64;
  int t = threadIdx.x;
  int lr = t>>2, lc4 = (t&3)*16;
#pragma unroll
  for (int i = 0; i < 4; ++i)
    *reinterpret_cast<f32x4*>(&tile[lr][lc4 + i*4]) =
        *reinterpret_cast<const f32x4*>(src + (size_t)(r0+lr)*C + c0 + lc4 + i*4);
  __syncthreads();
#pragma unroll
  for (int h = 0; h < 2; ++h) {
    int oc = h*32 + (t>>3);
    int ok = (t&7)*8;
    union { u16 a[8]; u32x4 v; } hb;
#pragma unroll
    for (int j = 0; j < 8; ++j)
      hb.a[j] = f2bf_bits(tile[ok+j][oc]);
    *reinterpret_cast<u32x4*>(dst + (size_t)(c0+oc)*R + r0 + ok) = hb.v;
  }
}

// ================= V transpose: vbf[tok][h*64+d] -> vT[bh][d][tok] =================
__global__ __launch_bounds__(256) void v_transpose_kernel(
    const u16* __restrict__ vbf, u16* __restrict__ vT)
{
  __shared__ u16 tile[64][72];
  int bh = blockIdx.y, b = bh >> 4, h = bh & 15;
  int t0 = blockIdx.x * 64;
  int t = threadIdx.x;
  int row = t >> 2, c16 = (t & 3) * 16;
  const u16* src = vbf + ((size_t)(b*T_SEQ + t0 + row))*D_MODEL + h*64 + c16;
  *reinterpret_cast<u32x4*>(&tile[row][c16])     = *reinterpret_cast<const u32x4*>(src);
  *reinterpret_cast<u32x4*>(&tile[row][c16 + 8]) = *reinterpret_cast<const u32x4*>(src + 8);
  __syncthreads();
  int d = row, k0 = c16;
  union { u16 a[16]; u32x4 v[2]; } o;
#pragma unroll
  for (int j = 0; j < 16; ++j) o.a[j] = tile[k0 + j][d];
  u16* dst = vT + ((size_t)bh*64 + d)*T_SEQ + t0 + k0;
  *reinterpret_cast<u32x4*>(dst)     = o.v[0];
  *reinterpret_cast<u32x4*>(dst + 8) = o.v[1];
}

// ================= QKV split GEMM, double-buffered (round-11 form) =================
__global__ __launch_bounds__(256) void qkv_gemm_kernel(
    const u16* __restrict__ Ahi, const u16* __restrict__ Alo,
    const u16* __restrict__ Bhi, const u16* __restrict__ Blo,
    const float* __restrict__ freqs,
    u16* __restrict__ qhi, u16* __restrict__ qlo,
    u16* __restrict__ khi, u16* __restrict__ klo,
    u16* __restrict__ vbf, float* __restrict__ kout, float* __restrict__ vout)
{
  const int K = D_MODEL;
  __shared__ __align__(16) u16 AhS[2][128*32], AlS[2][128*32],
                               BhS[2][128*32], BlS[2][128*32];   // 64 KB
  int tid = threadIdx.x, lane = tid & 63, wid = tid >> 6;
  int wm = wid >> 1, wn = wid & 1;
  int l15 = lane & 15, l4 = lane >> 4;
  size_t bm = (size_t)blockIdx.y * 128, bn = (size_t)blockIdx.x * 128;
  const u16* Ah0 = Ahi + bm*K;  const u16* Al0 = Alo + bm*K;
  const u16* Bh0 = Bhi + bn*K;  const u16* Bl0 = Blo + bn*K;
  f32x4 acc[4][4] = {};
  stage128x32(Ah0, K, 0, AhS[0], wid, lane);
  stage128x32(Al0, K, 0, AlS[0], wid, lane);
  stage128x32(Bh0, K, 0, BhS[0], wid, lane);
  stage128x32(Bl0, K, 0, BlS[0], wid, lane);
  __syncthreads();
  int cur = 0;
  for (int kt = 0; kt < K; kt += 32) {
    if (kt + 32 < K) {
      int nxt = cur ^ 1;
      stage128x32(Ah0, K, kt + 32, AhS[nxt], wid, lane);
      stage128x32(Al0, K, kt + 32, AlS[nxt], wid, lane);
      stage128x32(Bh0, K, kt + 32, BhS[nxt], wid, lane);
      stage128x32(Bl0, K, kt + 32, BlS[nxt], wid, lane);
    }
    bf16x8 ah[4], al[4];
#pragma unroll
    for (int mi = 0; mi < 4; ++mi) {
      int row = wm*64 + mi*16 + l15;
      ah[mi] = fragLDS(AhS[cur], row, l4, l15);
      al[mi] = fragLDS(AlS[cur], row, l4, l15);
    }
#pragma unroll
    for (int ni = 0; ni < 4; ++ni) {
      int row = wn*64 + ni*16 + l15;
      bf16x8 bh = fragLDS(BhS[cur], row, l4, l15);
      bf16x8 bl = fragLDS(BlS[cur], row, l4, l15);
#pragma unroll
      for (int mi = 0; mi < 4; ++mi) {
        acc[mi][ni] = MFMA16(ah[mi], bh, acc[mi][ni]);
        acc[mi][ni] = MFMA16(ah[mi], bl, acc[mi][ni]);
        acc[mi][ni] = MFMA16(al[mi], bh, acc[mi][ni]);
      }
    }
    __syncthreads();
    cur ^= 1;
  }
  int mat = (int)(bn >> 10);
  int colbase = (int)(bn & 1023);
  int evenl = !(lane & 1);
#pragma unroll
  for (int mi = 0; mi < 4; ++mi) {
#pragma unroll
    for (int r = 0; r < 4; ++r) {
      int tok = (int)bm + wm*64 + mi*16 + l4*4 + r;
      int t = tok & (T_SEQ - 1);
#pragma unroll
      for (int ni = 0; ni < 4; ++ni) {
        int col = colbase + wn*64 + ni*16 + l15;
        float v = acc[mi][ni][r];
        if (mat == 2) {
          float vp = __shfl_xor(v, 1);
          if (evenl) {
            u32 pk = (u32)cvt_bf16(v) | ((u32)cvt_bf16(vp) << 16);
            *reinterpret_cast<u32*>(vbf + (size_t)tok*D_MODEL + col) = pk;
            f32x2 fv; fv[0] = v; fv[1] = vp;
            *reinterpret_cast<f32x2*>(vout + (size_t)tok*D_MODEL + col) = fv;
          }
        } else {
          int d = col & 63, p = d >> 1;
          f32x2 cs = *reinterpret_cast<const f32x2*>(freqs + ((size_t)t*32 + p)*2);
          float partner = __shfl_xor(v, 1);
          float rot = (d & 1) ? (partner*cs[1] + v*cs[0]) : (v*cs[0] - partner*cs[1]);
          float rotp = __shfl_xor(rot, 1);
          if (evenl) {
            u16 h0 = cvt_bf16(rot), h1 = cvt_bf16(rotp);
            u32 hp = (u32)h0 | ((u32)h1 << 16);
            u32 lp = (u32)cvt_bf16(rot - bf2f(h0)) | ((u32)cvt_bf16(rotp - bf2f(h1)) << 16);
            if (mat == 0) {
              *reinterpret_cast<u32*>(qhi + (size_t)tok*D_MODEL + col) = hp;
              *reinterpret_cast<u32*>(qlo + (size_t)tok*D_MODEL + col) = lp;
            } else {
              *reinterpret_cast<u32*>(khi + (size_t)tok*D_MODEL + col) = hp;
              *reinterpret_cast<u32*>(klo + (size_t)tok*D_MODEL + col) = lp;
              f32x2 fv; fv[0] = rot; fv[1] = rotp;
              *reinterpret_cast<f32x2*>(kout + (size_t)tok*D_MODEL + col) = fv;
            }
          }
        }
      }
    }
  }
}

// ================= WO GEMM: 128x128 single-buffer (round-12 form) =================
__global__ __launch_bounds__(256) void wo_gemm_kernel(
    const u16* __restrict__ A, const u16* __restrict__ Bt,
    const float* __restrict__ resid, float* __restrict__ Cout)
{
  const int K = D_MODEL, N = D_MODEL;
  __shared__ __align__(16) u16 As[128*32], Bs[128*32];
  int tid = threadIdx.x, lane = tid & 63, wid = tid >> 6;
  int wm = wid >> 1, wn = wid & 1;
  int l15 = lane & 15, l4 = lane >> 4;
  size_t bm = (size_t)blockIdx.y * 128, bn = (size_t)blockIdx.x * 128;
  const u16* A0 = A + bm*K;  const u16* B0 = Bt + bn*K;
  f32x4 acc[4][4] = {};
  for (int kt = 0; kt < K; kt += 32) {
    __syncthreads();
    stage128x32(A0, K, kt, As, wid, lane);
    stage128x32(B0, K, kt, Bs, wid, lane);
    __syncthreads();
    bf16x8 a[4];
#pragma unroll
    for (int mi = 0; mi < 4; ++mi)
      a[mi] = fragLDS(As, wm*64 + mi*16 + l15, l4, l15);
#pragma unroll
    for (int ni = 0; ni < 4; ++ni) {
      bf16x8 b = fragLDS(Bs, wn*64 + ni*16 + l15, l4, l15);
#pragma unroll
      for (int mi = 0; mi < 4; ++mi)
        acc[mi][ni] = MFMA16(a[mi], b, acc[mi][ni]);
    }
  }
#pragma unroll
  for (int mi = 0; mi < 4; ++mi)
#pragma unroll
    for (int ni = 0; ni < 4; ++ni)
#pragma unroll
      for (int r = 0; r < 4; ++r) {
        size_t row = bm + wm*64 + mi*16 + l4*4 + r;
        size_t col = bn + wn*64 + ni*16 + l15;
        Cout[row*N + col] = resid[row*N + col] + acc[mi][ni][r];
      }
}

// ================= wg2[d][e] = sum_i wo[d][i]*ffnw[i]*gw[i][e] =================
__global__ __launch_bounds__(64) void wg2_kernel(
    const float* __restrict__ wo, const float* __restrict__ ffnw,
    const float* __restrict__ gw, float* __restrict__ wg2)
{
  int d = blockIdx.x, lane = threadIdx.x;
  const float* wr = wo + (size_t)d * D_MODEL;
  float acc[8] = {0,0,0,0,0,0,0,0};
#pragma unroll
  for (int i = 0; i < 4; ++i) {
    int c = lane*4 + i*256;
    f32x4 wv = *reinterpret_cast<const f32x4*>(wr + c);
    f32x4 fv = *reinterpret_cast<const f32x4*>(ffnw + c);
#pragma unroll
    for (int j = 0; j < 4; ++j) {
      float a = wv[j] * fv[j];
      f32x4 g0 = *reinterpret_cast<const f32x4*>(gw + (size_t)(c + j)*NEXP);
      f32x4 g1 = *reinterpret_cast<const f32x4*>(gw + (size_t)(c + j)*NEXP + 4);
      acc[0]+=a*g0[0]; acc[1]+=a*g0[1]; acc[2]+=a*g0[2]; acc[3]+=a*g0[3];
      acc[4]+=a*g1[0]; acc[5]+=a*g1[1]; acc[6]+=a*g1[2]; acc[7]+=a*g1[3];
    }
  }
#pragma unroll
  for (int off = 32; off >= 1; off >>= 1)
#pragma unroll
    for (int e = 0; e < 8; ++e) acc[e] += __shfl_xor(acc[e], off);
  if (lane == 0) {
#pragma unroll
    for (int e = 0; e < 8; ++e) wg2[(size_t)d*NEXP + e] = acc[e];
  }
}

// ================= Vg[t][h][e] =================
__global__ __launch_bounds__(256) void vg_kernel(
    const float* __restrict__ vf, const float* __restrict__ wg2, float* __restrict__ Vg)
{
  int tok = blockIdx.x * 4 + (threadIdx.x >> 6);
  int lane = threadIdx.x & 63;
  int hh = lane >> 2, part = lane & 3;
  const float* vr = vf + (size_t)tok * D_MODEL + hh*64 + part*16;
  const float* gr = wg2 + (size_t)(hh*64 + part*16) * NEXP;
  float acc[8] = {0,0,0,0,0,0,0,0};
#pragma unroll
  for (int i = 0; i < 4; ++i) {
    f32x4 vv = *reinterpret_cast<const f32x4*>(vr + i*4);
#pragma unroll
    for (int j = 0; j < 4; ++j) {
      float a = vv[j];
      f32x4 g0 = *reinterpret_cast<const f32x4*>(gr + (size_t)(i*4 + j)*NEXP);
      f32x4 g1 = *reinterpret_cast<const f32x4*>(gr + (size_t)(i*4 + j)*NEXP + 4);
      acc[0]+=a*g0[0]; acc[1]+=a*g0[1]; acc[2]+=a*g0[2]; acc[3]+=a*g0[3];
      acc[4]+=a*g1[0]; acc[5]+=a*g1[1]; acc[6]+=a*g1[2]; acc[7]+=a*g1[3];
    }
  }
#pragma unroll
  for (int off = 1; off < 4; off <<= 1)
#pragma unroll
    for (int e = 0; e < 8; ++e) acc[e] += __shfl_xor(acc[e], off);
  if (part == 0) {
#pragma unroll
    for (int e = 0; e < 8; ++e) Vg[((size_t)tok*NHEAD + hh)*NEXP + e] = acc[e];
  }
}

// ================= flash attention v5: K and V both staged via global_load_lds =================
__global__ __launch_bounds__(256) void attn_kernel(
    const u16* __restrict__ Qhi, const u16* __restrict__ Qlo,
    const u16* __restrict__ Khi, const u16* __restrict__ Klo,
    const u16* __restrict__ vT, const float* __restrict__ Vg,
    u16* __restrict__ Ob, float* __restrict__ raw_ao)
{
  int id = blockIdx.x;
  int bh = id & 31, b = bh >> 4, h = bh & 15;
  int rr_ = id >> 8, kk_ = (id >> 5) & 7;
  int qt = (rr_ == 0) ? (31 - kk_) : (rr_ == 1) ? (16 + kk_)
         : (rr_ == 2) ? (15 - kk_) : kk_;
  int tid = threadIdx.x, lane = tid & 63, wid = tid >> 6;
  int l15 = lane & 15, l4 = lane >> 4;

  __shared__ __align__(16) u16 VTs[64*64];
  __shared__ __align__(16) u16 Pl[4][16][72];
  __shared__ float VgS[64][12];
  __shared__ __align__(16) u16 KhS[64*64], KlS[64*64];

  const u16* vTb = vT + ((size_t)bh * 64) * T_SEQ;   // rows d, cols tok

  size_t qoff = ((size_t)(b*T_SEQ + qt*64 + wid*16)) * D_MODEL + h*64;
  bf16x8 qhiF[2], qloF[2];
#pragma unroll
  for (int s = 0; s < 2; ++s) {
    qhiF[s] = frag_b128(Qhi + qoff + (size_t)l15*D_MODEL + s*32 + l4*8);
    qloF[s] = frag_b128(Qlo + qoff + (size_t)l15*D_MODEL + s*32 + l4*8);
  }
  float m_r[4], l_r[4];
  f32x4 racc4[4][2] = {};
  f32x4 oacc[4] = {};
#pragma unroll
  for (int r = 0; r < 4; ++r) { m_r[r] = -1e30f; l_r[r] = 0.f; }

  for (int kt = 0; kt <= qt; ++kt) {
    __syncthreads();
    {
      const u16* kbH = Khi + ((size_t)(b*T_SEQ + kt*64))*D_MODEL + h*64;
      const u16* kbL = Klo + ((size_t)(b*T_SEQ + kt*64))*D_MODEL + h*64;
      stage64x64(kbH, D_MODEL, 0, KhS, wid, lane);
      stage64x64(kbL, D_MODEL, 0, KlS, wid, lane);
      stage64x64(vTb, T_SEQ, kt*64, VTs, wid, lane);   // [64 d][64 keys]
    }
    if (tid < 128) {
      int key = tid >> 1, eh = (tid & 1) * 4;
      const float* gsrc = Vg + ((size_t)(b*T_SEQ + kt*64 + key)*NHEAD + h)*NEXP + eh;
      *reinterpret_cast<f32x4*>(&VgS[key][eh]) = *reinterpret_cast<const f32x4*>(gsrc);
    }
    __syncthreads();

    f32x4 sacc[4] = {};
    __builtin_amdgcn_s_setprio(1);
#pragma unroll
    for (int n = 0; n < 4; ++n) {
#pragma unroll
      for (int s = 0; s < 2; ++s) {
        bf16x8 khiF = fragLDS64(KhS, n*16 + l15, s, l4, l15);
        bf16x8 kloF = fragLDS64(KlS, n*16 + l15, s, l4, l15);
        sacc[n] = MFMA16(qhiF[s], khiF, sacc[n]);
        sacc[n] = MFMA16(qhiF[s], kloF, sacc[n]);
        sacc[n] = MFMA16(qloF[s], khiF, sacc[n]);
      }
    }
    __builtin_amdgcn_s_setprio(0);
#pragma unroll
    for (int n = 0; n < 4; ++n)
#pragma unroll
      for (int r = 0; r < 4; ++r)
        sacc[n][r] *= 0.125f;
    if (kt == qt) {
      int q0 = qt*64 + wid*16 + l4*4;
      int k00 = kt*64 + l15;
#pragma unroll
      for (int n = 0; n < 4; ++n)
#pragma unroll
        for (int r = 0; r < 4; ++r)
          if (k00 + n*16 > q0 + r) sacc[n][r] = -1e30f;
    }
    float rm[4];
#pragma unroll
    for (int r = 0; r < 4; ++r) {
      float v = fmaxf(fmaxf(sacc[0][r], sacc[1][r]), fmaxf(sacc[2][r], sacc[3][r]));
#pragma unroll
      for (int off = 1; off < 16; off <<= 1) v = fmaxf(v, __shfl_xor(v, off));
      rm[r] = v;
    }
    int needp = (rm[0] > m_r[0]+8.f) | (rm[1] > m_r[1]+8.f) |
                (rm[2] > m_r[2]+8.f) | (rm[3] > m_r[3]+8.f);
    if (__any(needp)) {
#pragma unroll
      for (int r = 0; r < 4; ++r) {
        float mn = fmaxf(m_r[r], rm[r]);
        float corr = __expf(m_r[r] - mn);
        m_r[r] = mn;
        l_r[r] *= corr;
        racc4[r][0] *= corr; racc4[r][1] *= corr;
#pragma unroll
        for (int n = 0; n < 4; ++n) oacc[n][r] *= corr;
      }
    }
#pragma unroll
    for (int r = 0; r < 4; ++r) {
      float rs = 0.f;
#pragma unroll
      for (int n = 0; n < 4; ++n) {
        float pp = __expf(sacc[n][r] - m_r[r]);
        sacc[n][r] = pp;
        rs += pp;
      }
#pragma unroll
      for (int off = 1; off < 16; off <<= 1) rs += __shfl_xor(rs, off);
      l_r[r] += rs;
    }
#pragma unroll
    for (int n = 0; n < 4; ++n)
#pragma unroll
      for (int r = 0; r < 4; ++r)
        Pl[wid][l4*4 + r][n*16 + l15] = cvt_bf16(sacc[n][r]);
#pragma unroll
    for (int n = 0; n < 4; ++n) {
      f32x4 g0 = *reinterpret_cast<const f32x4*>(&VgS[n*16 + l15][0]);
      f32x4 g1 = *reinterpret_cast<const f32x4*>(&VgS[n*16 + l15][4]);
#pragma unroll
      for (int r = 0; r < 4; ++r) {
        float pp = sacc[n][r];
        racc4[r][0] += g0 * pp;
        racc4[r][1] += g1 * pp;
      }
    }
    __builtin_amdgcn_s_setprio(1);
#pragma unroll
    for (int s = 0; s < 2; ++s) {
      bf16x8 pa = frag_b128(&Pl[wid][l15][s*32 + l4*8]);
#pragma unroll
      for (int n = 0; n < 4; ++n) {
        bf16x8 vb8 = fragLDS64(VTs, n*16 + l15, s, l4, l15);
        oacc[n] = MFMA16(pa, vb8, oacc[n]);
      }
    }
    __builtin_amdgcn_s_setprio(0);
  }
  float inv[4];
#pragma unroll
  for (int r = 0; r < 4; ++r) inv[r] = 1.0f / l_r[r];
  size_t obase = ((size_t)(b*T_SEQ + qt*64 + wid*16))*D_MODEL + h*64;
#pragma unroll
  for (int n = 0; n < 4; ++n)
#pragma unroll
    for (int r = 0; r < 4; ++r)
      Ob[obase + (size_t)(l4*4 + r)*D_MODEL + n*16 + l15] = cvt_bf16(oacc[n][r]*inv[r]);
  float rv[4][8];
#pragma unroll
  for (int r = 0; r < 4; ++r)
#pragma unroll
    for (int e = 0; e < 8; ++e)
      rv[r][e] = (e < 4) ? racc4[r][0][e] : racc4[r][1][e-4];
#pragma unroll
  for (int off = 1; off < 16; off <<= 1)
#pragma unroll
    for (int r = 0; r < 4; ++r)
#pragma unroll
      for (int e = 0; e < 8; ++e)
        rv[r][e] += __shfl_xor(rv[r][e], off);
  if (l15 == 0) {
#pragma unroll
    for (int r = 0; r < 4; ++r) {
      size_t tokg = (size_t)(b*T_SEQ) + qt*64 + wid*16 + l4*4 + r;
#pragma unroll
      for (int e = 0; e < 8; ++e)
        raw_ao[(tokg*NHEAD + h)*NEXP + e] = rv[r][e]*inv[r];
    }
  }
}

// ================= gate: fp32 logits, top-2 =================
__global__ void zero_counts_kernel(int* counts) {
  if (threadIdx.x < NEXP) counts[threadIdx.x] = 0;
}

__global__ __launch_bounds__(256) void gate2_kernel(
    const float* __restrict__ x, const float* __restrict__ x2,
    const float* __restrict__ ffnw, const float* __restrict__ gw,
    const float* __restrict__ raw_ao,
    int* __restrict__ gidx, float* __restrict__ gwt, int* __restrict__ counts)
{
  int tok = blockIdx.x * 4 + (threadIdx.x >> 6);
  int lane = threadIdx.x & 63;
  const float* xr = x + (size_t)tok * D_MODEL;
  const float* x2r = x2 + (size_t)tok * D_MODEL;
  float ss = 0.f;
  float lg[8] = {0,0,0,0,0,0,0,0};
#pragma unroll
  for (int i = 0; i < 4; ++i) {
    int d = lane*4 + i*256;
    f32x4 xv = *reinterpret_cast<const f32x4*>(xr + d);
    f32x4 x2v = *reinterpret_cast<const f32x4*>(x2r + d);
    f32x4 wv = *reinterpret_cast<const f32x4*>(ffnw + d);
    ss += x2v[0]*x2v[0] + x2v[1]*x2v[1] + x2v[2]*x2v[2] + x2v[3]*x2v[3];
#pragma unroll
    for (int j = 0; j < 4; ++j) {
      float a = xv[j]*wv[j];
      f32x4 g0 = *reinterpret_cast<const f32x4*>(gw + (size_t)(d + j)*NEXP);
      f32x4 g1 = *reinterpret_cast<const f32x4*>(gw + (size_t)(d + j)*NEXP + 4);
      lg[0]+=a*g0[0]; lg[1]+=a*g0[1]; lg[2]+=a*g0[2]; lg[3]+=a*g0[3];
      lg[4]+=a*g1[0]; lg[5]+=a*g1[1]; lg[6]+=a*g1[2]; lg[7]+=a*g1[3];
    }
  }
#pragma unroll
  for (int off = 1; off < 64; off <<= 1) {
    ss += __shfl_xor(ss, off);
#pragma unroll
    for (int e = 0; e < 8; ++e) lg[e] += __shfl_xor(lg[e], off);
  }
  float ah[8] = {0,0,0,0,0,0,0,0};
  if (lane < 16) {
    const float* ar = raw_ao + ((size_t)tok*NHEAD + lane)*NEXP;
#pragma unroll
    for (int e = 0; e < 8; ++e) ah[e] = ar[e];
  }
#pragma unroll
  for (int off = 1; off < 16; off <<= 1)
#pragma unroll
    for (int e = 0; e < 8; ++e) ah[e] += __shfl_xor(ah[e], off);
  if (lane == 0) {
    float rms = rsqrtf(ss*(1.0f/D_MODEL) + 1e-6f);
    float lo_[8], pp[8];
    float mx = -1e30f;
#pragma unroll
    for (int e = 0; e < 8; ++e) { lo_[e] = (lg[e] + ah[e]) * rms; mx = fmaxf(mx, lo_[e]); }
    float sum = 0.f;
#pragma unroll
    for (int e = 0; e < 8; ++e) { pp[e] = __expf(lo_[e] - mx); sum += pp[e]; }
    float isum = 1.0f/sum;
#pragma unroll
    for (int e = 0; e < 8; ++e) pp[e] *= isum;
    int i0 = 0;
    for (int e = 1; e < 8; ++e) if (pp[e] > pp[i0]) i0 = e;
    int i1 = (i0 == 0) ? 1 : 0;
    for (int e = 0; e < 8; ++e) if (e != i0 && pp[e] > pp[i1]) i1 = e;
    float v0 = pp[i0], v1 = pp[i1];
    float wnorm = 1.0f/(v0 + v1 + 1e-8f);
    gidx[2*tok] = i0; gidx[2*tok+1] = i1;
    gwt[2*tok] = v0*wnorm; gwt[2*tok+1] = v1*wnorm;
    atomicAdd(&counts[i0], 1); atomicAdd(&counts[i1], 1);
  }
}

// ================= routing =================
__global__ __launch_bounds__(256) void scan_kernel(
    const int* __restrict__ counts, int* __restrict__ base, int* __restrict__ fill,
    int* __restrict__ blk_expert, int* __restrict__ perm_token)
{
  if (threadIdx.x == 0) {
    int b = 0, blk = 0;
    for (int e = 0; e < NEXP; ++e) {
      base[e] = b;
      fill[e] = 0;
      int nb = (counts[e] + 127) >> 7;
      for (int i = 0; i < nb; ++i) blk_expert[blk++] = e;
      b += nb << 7;
    }
    for (; blk < MAXBLK; ++blk) blk_expert[blk] = -1;
  }
  for (int i = threadIdx.x; i < SLOTS; i += 256) perm_token[i] = -1;
}

__global__ __launch_bounds__(256) void scatter_kernel(
    const int* __restrict__ gidx, const int* __restrict__ base, int* __restrict__ fill,
    int* __restrict__ perm_token, int* __restrict__ tok_slot)
{
  int t = blockIdx.x * 256 + threadIdx.x;
  if (t >= NTOK) return;
#pragma unroll
  for (int r = 0; r < 2; ++r) {
    int e = gidx[2*t + r];
    int pos = base[e] + atomicAdd(&fill[e], 1);
    perm_token[pos] = t;
    tok_slot[2*t + r] = pos;
  }
}

// ================= MoE GEMM1: BN=64, BK=64 =================
__global__ __launch_bounds__(256) void moe_gemm1_kernel(
    const u16* __restrict__ Ah, const u16* __restrict__ W1t, const u16* __restrict__ W3t,
    const int* __restrict__ perm_token, const int* __restrict__ blk_expert,
    u16* __restrict__ tbuf)
{
  int mb = blockIdx.y;
  int e = blk_expert[mb];
  if (e < 0) return;
  const int K = D_MODEL;
  __shared__ __align__(16) u16 As[128*64], B1s[64*64], B3s[64*64];  // 32 KB
  int tid = threadIdx.x, lane = tid & 63, wid = tid >> 6;
  int wm = wid >> 1, wn = wid & 1;
  int l15 = lane & 15, l4 = lane >> 4;
  size_t bn = (size_t)blockIdx.x * 64;
  const u16* w1e = W1t + (size_t)e * HID_DIM * D_MODEL + bn*K;
  const u16* w3e = W3t + (size_t)e * HID_DIM * D_MODEL + bn*K;
  int rl = lane >> 3, cc = lane & 7;
  int tokA[4];
#pragma unroll
  for (int g = 0; g < 4; ++g) {
    int row = wid*32 + g*8 + rl;
    int t = perm_token[mb*128 + row];
    tokA[g] = t < 0 ? 0 : t;
  }
  f32x4 acc1[4][2] = {}, acc3[4][2] = {};
  for (int kt = 0; kt < K; kt += 64) {
    __syncthreads();
#pragma unroll
    for (int g = 0; g < 4; ++g) {
      int row = wid*32 + g*8 + rl;
      int chunk = cc ^ (row & 7);
      gload16(Ah + (size_t)tokA[g]*K + kt + chunk*8, As + (size_t)(wid*32 + g*8)*64);
    }
    stage64x64(w1e, K, kt, B1s, wid, lane);
    stage64x64(w3e, K, kt, B3s, wid, lane);
    __syncthreads();
#pragma unroll
    for (int s = 0; s < 2; ++s) {
      bf16x8 a[4];
#pragma unroll
      for (int mi = 0; mi < 4; ++mi)
        a[mi] = fragLDS64(As, wm*64 + mi*16 + l15, s, l4, l15);
#pragma unroll
      for (int ni = 0; ni < 2; ++ni) {
        int row = wn*32 + ni*16 + l15;
        bf16x8 b1 = fragLDS64(B1s, row, s, l4, l15);
        bf16x8 b3 = fragLDS64(B3s, row, s, l4, l15);
#pragma unroll
        for (int mi = 0; mi < 4; ++mi) {
          acc1[mi][ni] = MFMA16(a[mi], b1, acc1[mi][ni]);
          acc3[mi][ni] = MFMA16(a[mi], b3, acc3[mi][ni]);
        }
      }
    }
  }
  int evenl = !(lane & 1);
#pragma unroll
  for (int mi = 0; mi < 4; ++mi)
#pragma unroll
    for (int ni = 0; ni < 2; ++ni)
#pragma unroll
      for (int r = 0; r < 4; ++r) {
        size_t slot = (size_t)mb*128 + wm*64 + mi*16 + l4*4 + r;
        size_t col = bn + wn*32 + ni*16 + l15;
        float h1 = acc1[mi][ni][r], h3 = acc3[mi][ni][r];
        float t = h1 * __builtin_amdgcn_rcpf(1.0f + __expf(-h1)) * h3;
        float tp = __shfl_xor(t, 1);
        if (evenl) {
          u32 pk = (u32)cvt_bf16(t) | ((u32)cvt_bf16(tp) << 16);
          *reinterpret_cast<u32*>(tbuf + slot*HID_DIM + col) = pk;
        }
      }
}

// ================= MoE GEMM2: BK=32 single-buffer (round-12 form) =================
__global__ __launch_bounds__(256) void moe_gemm2_kernel(
    const u16* __restrict__ tbuf, const u16* __restrict__ W2t,
    const int* __restrict__ blk_expert, u16* __restrict__ ybuf)
{
  int mb = blockIdx.y;
  int e = blk_expert[mb];
  if (e < 0) return;
  const int K = HID_DIM, N = D_MODEL;
  __shared__ __align__(16) u16 As[128*32], Bs[128*32];   // 16 KB
  int tid = threadIdx.x, lane = tid & 63, wid = tid >> 6;
  int wm = wid >> 1, wn = wid & 1;
  int l15 = lane & 15, l4 = lane >> 4;
  size_t bm = (size_t)mb * 128, bn = (size_t)blockIdx.x * 128;
  const u16* A0 = tbuf + bm*K;
  const u16* B0 = W2t + (size_t)e * D_MODEL * HID_DIM + bn*K;
  f32x4 acc[4][4] = {};
  for (int kt = 0; kt < K; kt += 32) {
    __syncthreads();
    stage128x32(A0, K, kt, As, wid, lane);
    stage128x32(B0, K, kt, Bs, wid, lane);
    __syncthreads();
    bf16x8 a[4];
#pragma unroll
    for (int mi = 0; mi < 4; ++mi)
      a[mi] = fragLDS(As, wm*64 + mi*16 + l15, l4, l15);
#pragma unroll
    for (int ni = 0; ni < 4; ++ni) {
      bf16x8 b = fragLDS(Bs, wn*64 + ni*16 + l15, l4, l15);
#pragma unroll
      for (int mi = 0; mi < 4; ++mi)
        acc[mi][ni] = MFMA16(a[mi], b, acc[mi][ni]);
    }
  }
  int evenl = !(lane & 1);
#pragma unroll
  for (int mi = 0; mi < 4; ++mi)
#pragma unroll
    for (int ni = 0; ni < 4; ++ni)
#pragma unroll
      for (int r = 0; r < 4; ++r) {
        float v = acc[mi][ni][r];
        float vp = __shfl_xor(v, 1);
        if (evenl) {
          size_t slot = bm + wm*64 + mi*16 + l4*4 + r;
          size_t col = bn + wn*64 + ni*16 + l15;
          u32 pk = (u32)cvt_bf16(v) | ((u32)cvt_bf16(vp) << 16);
          *reinterpret_cast<u32*>(ybuf + slot*N + col) = pk;
        }
      }
}

// ================= combine =================
__global__ __launch_bounds__(256) void combine_kernel(
    const float* __restrict__ x2, const u16* __restrict__ ybuf,
    const int* __restrict__ tok_slot, const float* __restrict__ gwt,
    float* __restrict__ xout)
{
  int t = blockIdx.x;
  int c = threadIdx.x * 4;
  int s0 = tok_slot[2*t], s1 = tok_slot[2*t+1];
  float w0 = gwt[2*t], w1 = gwt[2*t+1];
  f32x4 xv = *reinterpret_cast<const f32x4*>(x2 + (size_t)t * D_MODEL + c);
  const u16* y0 = ybuf + (size_t)s0 * D_MODEL + c;
  const u16* y1 = ybuf + (size_t)s1 * D_MODEL + c;
  f32x4 o;
#pragma unroll
  for (int j = 0; j < 4; ++j)
    o[j] = xv[j] + w0 * bf2f(y0[j]) + w1 * bf2f(y1[j]);
  *reinterpret_cast<f32x4*>(xout + (size_t)t * D_MODEL + c) = o;
}

// ================= host launch =================
extern "C" void kernel_launch(void* const* d_in, const int* in_sizes, int n_in,
                              void* d_out, int out_size, void* d_ws, size_t ws_size,
                              hipStream_t stream)
{
  (void)in_sizes; (void)n_in; (void)out_size; (void)ws_size;
  const float* x     = (const float*)d_in[0];
  const float* freqs = (const float*)d_in[1];
  const float* attnw = (const float*)d_in[3];
  const float* ffnw  = (const float*)d_in[4];
  const float* wq    = (const float*)d_in[5];
  const float* wk    = (const float*)d_in[6];
  const float* wv    = (const float*)d_in[7];
  const float* wo    = (const float*)d_in[8];
  const float* gw    = (const float*)d_in[9];
  const float* w1    = (const float*)d_in[10];
  const float* w2    = (const float*)d_in[11];
  const float* w3    = (const float*)d_in[12];
  float* xout = (float*)d_out;
  float* kout = xout + (size_t)NTOK * D_MODEL;
  float* vout = kout + (size_t)NTOK * D_MODEL;

  const size_t PLANE = (size_t)NTOK * D_MODEL * 2;      // 8,388,608
  const size_t QKVT  = (size_t)3 * D_MODEL * D_MODEL * 2; // 6,291,456
  const size_t TBUFB = (size_t)SLOTS * HID_DIM * 2;     // 37,748,736
  const size_t WEXP  = (size_t)NEXP * D_MODEL * HID_DIM * 2; // 33,554,432
  char* base = (char*)d_ws;
  // region P: [0, 37.75M) : hhi|hlo|wqkvT planes / woT ; later tbuf
  u16* hhi      = (u16*)(base);
  u16* hlo      = (u16*)(base + PLANE);
  u16* wqkvT_hi = (u16*)(base + 2*PLANE);
  u16* wqkvT_lo = (u16*)(base + 2*PLANE + QKVT);
  u16* woT      = (u16*)(base + 2*PLANE);               // after qkv gemm
  u16* tbuf     = (u16*)(base);                          // moe1..moe2
  // region Q: q/k planes + vbf ; later w1T ; later ybuf
  char* Qb = base + TBUFB;
  u16* qhi = (u16*)(Qb);
  u16* qlo = (u16*)(Qb + PLANE);
  u16* khi = (u16*)(Qb + 2*PLANE);
  u16* klo = (u16*)(Qb + 3*PLANE);
  u16* vbf = (u16*)(Qb + 4*PLANE);
  u16* w1T  = (u16*)(Qb);                                // after attn
  u16* ybuf = (u16*)(Qb);                                // after moe1
  // region S: aobf | vT ; later w3T ; later w2T
  char* Sb = Qb + 5*PLANE;
  u16* aobf = (u16*)(Sb);
  u16* vT   = (u16*)(Sb + PLANE);                        // [32 bh][64 d][2048 tok]
  u16* w3T  = (u16*)(Sb);                                // after wo gemm (aobf+vT dead)
  u16* w2T  = (u16*)(Sb);                                // after moe1
  // region T: hf ; region X: x2
  char* Tb = Sb + WEXP;
  u16* hf = (u16*)(Tb);
  float* x2 = (float*)(Tb + PLANE);
  // smalls
  char* p = Tb + PLANE + (size_t)NTOK * D_MODEL * 4;
  float* wg2    = (float*)p;  p += 32768;
  float* Vg     = (float*)p;  p += (size_t)NTOK*NHEAD*NEXP*4;
  float* raw_ao = (float*)p;  p += (size_t)NTOK*NHEAD*NEXP*4;
  int*   gidx   = (int*)p;    p += 32768;
  float* gwt    = (float*)p;  p += 32768;
  int*   tok_slot = (int*)p;  p += 32768;
  int*   perm   = (int*)p;    p += SLOTS*4;
  int*   counts = (int*)p;
  int*   base_  = counts + 8;
  int*   fill_  = counts + 16;
  int*   blk_e  = counts + 24;

  dim3 blk(256);
  // 1. norms + small precomputes
  rmsnorm_kernel<1><<<NTOK, blk, 0, stream>>>(x, attnw, hhi, hlo);
  wg2_kernel<<<D_MODEL, 64, 0, stream>>>(wo, ffnw, gw, wg2);
  zero_counts_kernel<<<1, 64, 0, stream>>>(counts);
  // 2. fused transpose+split wq/wk/wv (one launch, z=3)
  dim3 tg3(16, 16, 3);
  transpose_qkv_kernel<<<tg3, blk, 0, stream>>>(wq, wk, wv, wqkvT_hi, wqkvT_lo);
  // 3. fused QKV split-GEMM + rope epilogue (round-11 dbuf, BN=128)
  dim3 gqkv(24, 32);
  qkv_gemm_kernel<<<gqkv, blk, 0, stream>>>(hhi, hlo, wqkvT_hi, wqkvT_lo, freqs,
                                            qhi, qlo, khi, klo, vbf, kout, vout);
  // 4. V transpose, woT, Vg
  dim3 gvt(T_SEQ/64, 32);
  v_transpose_kernel<<<gvt, blk, 0, stream>>>(vbf, vT);
  dim3 tg(16, 16);
  transpose_kernel<0><<<tg, blk, 0, stream>>>(wo, woT, nullptr, D_MODEL, D_MODEL);
  vg_kernel<<<NTOK/4, blk, 0, stream>>>(vout, wg2, Vg);
  // 5. attention: 1024 blocks, zig-zag balanced qt, K+V staged in LDS
  attn_kernel<<<dim3(1024), blk, 0, stream>>>(qhi, qlo, khi, klo, vT, Vg, aobf, raw_ao);
  // 6. WO gemm (single-buffer), then fused w1/w3 transpose (both regions dead)
  dim3 g88(D_MODEL/128, NTOK/128);
  wo_gemm_kernel<<<g88, blk, 0, stream>>>(aobf, woT, x, x2);
  dim3 tw13(HID_DIM/64, D_MODEL/64, 2*NEXP);
  transpose_w13_kernel<<<tw13, blk, 0, stream>>>(w1, w3, w1T, w3T);
  // 7. norm, gate, routing
  rmsnorm_kernel<0><<<NTOK, blk, 0, stream>>>(x2, ffnw, hf, nullptr);
  gate2_kernel<<<NTOK/4, blk, 0, stream>>>(x, x2, ffnw, gw, raw_ao, gidx, gwt, counts);
  scan_kernel<<<1, blk, 0, stream>>>(counts, base_, fill_, blk_e, perm);
  scatter_kernel<<<NTOK/256, blk, 0, stream>>>(gidx, base_, fill_, perm, tok_slot);
  // 8. MoE gemm1: BN=64 grid
  dim3 g1(HID_DIM/64, MAXBLK);
  moe_gemm1_kernel<<<g1, blk, 0, stream>>>(hf, w1T, w3T, perm, blk_e, tbuf);
  // 9. w2T, gemm2 (single-buffer)
  dim3 tw2(D_MODEL/64, HID_DIM/64, NEXP);
  transpose_kernel<0><<<tw2, blk, 0, stream>>>(w2, w2T, nullptr, HID_DIM, D_MODEL);
  dim3 g2(D_MODEL/128, MAXBLK);
  moe_gemm2_kernel<<<g2, blk, 0, stream>>>(tbuf, w2T, blk_e, ybuf);
  // 10. combine
  combine_kernel<<<NTOK, blk, 0, stream>>>(x2, ybuf, tok_slot, gwt, xout);
}